// Round 10
// baseline (345.105 us; speedup 1.0000x reference)
//
#include <hip/hip_runtime.h>
#include <cstdint>
#include <cstddef>

// ---------- types ----------
typedef __attribute__((ext_vector_type(8))) __bf16 bf16x8;
typedef __attribute__((ext_vector_type(4))) float floatx4;
typedef __attribute__((ext_vector_type(4))) int intx4;
typedef __attribute__((ext_vector_type(8))) int intx8;

__device__ __forceinline__ unsigned short f2bf(float f) {
    unsigned int u = __float_as_uint(f);
    u += 0x7fffu + ((u >> 16) & 1u);      // RNE
    return (unsigned short)(u >> 16);
}

__device__ __forceinline__ void async_copy16(const void* gp, void* lp) {
    __builtin_amdgcn_global_load_lds(
        (__attribute__((address_space(1))) void*)gp,
        (__attribute__((address_space(3))) void*)lp,
        16, 0, 0);
}

// ---------- constants ----------
#define CCH 512
#define AREA 4096
#define NGRP 32
#define TB (AREA * CCH)        // per-batch tensor elements (2097152)

// =====================================================================
// TN GEMM (bf16 inputs): C[m][n] = alpha * sum_k A[m][k]*B[n][k]
// BIAS_MODE: 0 none, 1 per-m, 2 per-n. OutT: float | bf16 | fp8.
// 2-phase 128^2 structure, 3-4 blocks/CU.
// =====================================================================
template<int TBM, int TBN, typename OutT, int BIAS_MODE, bool RESID>
__global__ __launch_bounds__(256, 4) void gemm_tn(
    const unsigned short* __restrict__ A, const unsigned short* __restrict__ B,
    OutT* __restrict__ C, const float* __restrict__ bias,
    const float* __restrict__ resid,
    int M, int N, int K, int lda, int ldb, int ldc,
    long sA, long sB, long sC, long sR, float alpha)
{
    constexpr int BK = 64;
    constexpr int MT = TBM / 32;
    constexpr int NT = TBN / 32;
    constexpr int NAR = (TBM * BK) / (256 * 8);
    constexpr int NBR = (TBN * BK) / (256 * 8);
    __shared__ __align__(16) unsigned char smem[(TBM + TBN) * BK * 2];
    unsigned short* As = (unsigned short*)smem;
    unsigned short* Bs = (unsigned short*)(smem + TBM * BK * 2);

    const int tid  = threadIdx.x;
    const int wave = tid >> 6;
    const int lane = tid & 63;
    const int wm = (wave >> 1) * (MT * 16);
    const int wn = (wave & 1) * (NT * 16);
    const int lr = lane & 15;
    const int lq = lane >> 4;
    const int sw = lr & 7;

    const int m0 = blockIdx.y * TBM;
    const int n0 = blockIdx.x * TBN;
    A += (size_t)blockIdx.z * sA + (size_t)m0 * lda;
    B += (size_t)blockIdx.z * sB + (size_t)n0 * ldb;

    unsigned int aOff[NAR], bOff[NBR];
#pragma unroll
    for (int r = 0; r < NAR; ++r) {
        int idx = r * 256 + tid;
        int row = idx >> 3;
        int scc = (idx & 7) ^ (row & 7);
        aOff[r] = (unsigned int)(row * lda + (scc << 3)) * 2u;
    }
#pragma unroll
    for (int r = 0; r < NBR; ++r) {
        int idx = r * 256 + tid;
        int row = idx >> 3;
        int scc = (idx & 7) ^ (row & 7);
        bOff[r] = (unsigned int)(row * ldb + (scc << 3)) * 2u;
    }
    const int aBase = (wm + lr) * (BK * 2) + ((lq ^ sw) << 4);
    const int bBase = (wn + lr) * (BK * 2) + ((lq ^ sw) << 4);

    floatx4 acc[MT][NT];
#pragma unroll
    for (int i = 0; i < MT; ++i)
#pragma unroll
        for (int j = 0; j < NT; ++j) acc[i][j] = floatx4{0.f, 0.f, 0.f, 0.f};

    const char* Ab = (const char*)A;
    const char* Bb = (const char*)B;
    for (int k0 = 0; k0 < K; k0 += BK) {
#pragma unroll
        for (int r = 0; r < NAR; ++r)
            async_copy16(Ab + aOff[r], &As[(r * 256 + tid) * 8]);
#pragma unroll
        for (int r = 0; r < NBR; ++r)
            async_copy16(Bb + bOff[r], &Bs[(r * 256 + tid) * 8]);
        Ab += BK * 2;
        Bb += BK * 2;
        __syncthreads();
#pragma unroll
        for (int ks = 0; ks < BK / 32; ++ks) {
            bf16x8 af[MT], bg[NT];
#pragma unroll
            for (int i = 0; i < MT; ++i)
                af[i] = *(const bf16x8*)((const char*)As +
                        ((aBase ^ (ks << 6)) + i * (16 * BK * 2)));
#pragma unroll
            for (int j = 0; j < NT; ++j)
                bg[j] = *(const bf16x8*)((const char*)Bs +
                        ((bBase ^ (ks << 6)) + j * (16 * BK * 2)));
#pragma unroll
            for (int i = 0; i < MT; ++i)
#pragma unroll
                for (int j = 0; j < NT; ++j)
                    acc[i][j] = __builtin_amdgcn_mfma_f32_16x16x32_bf16(
                        af[i], bg[j], acc[i][j], 0, 0, 0);
        }
        __syncthreads();
    }

    // epilogue: C/D layout col=lane&15, row=(lane>>4)*4+reg
    C += (size_t)blockIdx.z * sC;
    if constexpr (RESID) resid += (size_t)blockIdx.z * sR;
    float bn[NT];
    if constexpr (BIAS_MODE == 2) {
#pragma unroll
        for (int j = 0; j < NT; ++j) bn[j] = bias[n0 + wn + j * 16 + lr];
    }
#pragma unroll
    for (int i = 0; i < MT; ++i) {
        const int mbase = m0 + wm + i * 16 + lq * 4;
        float bm4[4];
        if constexpr (BIAS_MODE == 1) {
#pragma unroll
            for (int r = 0; r < 4; ++r) bm4[r] = bias[mbase + r];
        }
#pragma unroll
        for (int j = 0; j < NT; ++j) {
            const int nn = n0 + wn + j * 16 + lr;
#pragma unroll
            for (int r = 0; r < 4; ++r) {
                float val = acc[i][j][r] * alpha;
                if constexpr (BIAS_MODE == 1) val += bm4[r];
                if constexpr (BIAS_MODE == 2) val += bn[j];
                size_t off = (size_t)(mbase + r) * ldc + nn;
                if constexpr (RESID) val += resid[off];
                if constexpr (sizeof(OutT) == 1) {
                    int pk = __builtin_amdgcn_cvt_pk_fp8_f32(val, val, 0, false);
                    C[off] = (OutT)(pk & 0xff);
                } else if constexpr (sizeof(OutT) == 2) {
                    C[off] = (OutT)f2bf(val);
                } else {
                    C[off] = val;
                }
            }
        }
    }
}

// =====================================================================
// S+exp via MX-scaled fp8 MFMA 16x16x128 (scales=1.0), BKB=128 / 32 KB.
// Shape change 32x32x64 -> 16x16x128: lanes read 16 distinct rows (not
// 32) over 8 swizzle slots -> 2-way bank aliasing (free, m136) instead
// of pigeonhole-forced 4-way. K=128 spans the whole k-tile: no kh loop.
// A-frag: row = base + (lane&15), k-bytes [(lane>>4)*32, +32) = chunks
// c0=(lane>>4)*2, c0+1; swizzled addr = row*128 + ((c0^(row&7))<<4),
// partner at ^16; row&7 invariant under +16 so frag i = base + i*2048.
// C/D 16x16 layout (HW-verified r1): col = lane&15, row = (lane>>4)*4+reg.
// launch_bounds(256,4): VGPR budget 128; est. ~120 live (64 acc + 32 af
// + 8 bg transient). (256,5) is a spill trap — occupancy steps at
// VGPR={64,128,256} only.
// =====================================================================
__global__ __launch_bounds__(256, 4) void s_mx(
    const unsigned char* __restrict__ A, const unsigned char* __restrict__ B,
    unsigned char* __restrict__ P, float* __restrict__ lsum)
{
    constexpr int BKB = 128;
    __shared__ __align__(16) unsigned char smem[32768];
    unsigned char* As = smem;            // 16 KB
    unsigned char* Bs = smem + 16384;    // 16 KB

    const int tid  = threadIdx.x;
    const int wave = tid >> 6;
    const int lane = tid & 63;
    const int lr = lane & 15;
    const int lq = lane >> 4;
    const int wm = (wave >> 1) * 64;   // m (P-col) half
    const int wn = (wave & 1) * 64;    // n (P-row) half

    const int m0 = blockIdx.y * 128;
    const int n0 = blockIdx.x * 128;
    const int bz = blockIdx.z;

    const unsigned char* Ap = A + (size_t)bz * ((size_t)AREA * 1024) +
                              (size_t)m0 * 1024;
    const unsigned char* Bp = B + (size_t)bz * ((size_t)AREA * 1024) +
                              (size_t)n0 * 1024;

    // staging: 1024 16B-chunks per side, 8 chunks/row, XOR row&7 swizzle
    unsigned int aOff[4];
#pragma unroll
    for (int r = 0; r < 4; ++r) {
        int idx = r * 256 + tid;
        int row = idx >> 3;
        int scc = (idx & 7) ^ (row & 7);
        aOff[r] = (unsigned int)(row * 1024 + (scc << 4));
    }
    const int ra = wm + lr;
    const int rb = wn + lr;
    const int aB = ra * BKB + (((lq << 1) ^ (ra & 7)) << 4);
    const int bB = rb * BKB + (((lq << 1) ^ (rb & 7)) << 4);

    floatx4 acc[4][4];    // [ia = m frag][jb = n frag]
#pragma unroll
    for (int i = 0; i < 4; ++i)
#pragma unroll
        for (int j = 0; j < 4; ++j) acc[i][j] = floatx4{0.f, 0.f, 0.f, 0.f};

    for (int k0 = 0; k0 < 512; k0 += BKB) {
#pragma unroll
        for (int r = 0; r < 4; ++r)
            async_copy16(Ap + k0 + aOff[r], &As[(r * 256 + tid) * 16]);
#pragma unroll
        for (int r = 0; r < 4; ++r)
            async_copy16(Bp + k0 + aOff[r], &Bs[(r * 256 + tid) * 16]);
        __syncthreads();
        intx8 af[4];
#pragma unroll
        for (int i = 0; i < 4; ++i) {
            int o = aB + i * 2048;
            intx4 lo = *(const intx4*)&As[o];
            intx4 hi = *(const intx4*)&As[o ^ 16];
            af[i] = __builtin_shufflevector(lo, hi, 0, 1, 2, 3, 4, 5, 6, 7);
        }
#pragma unroll
        for (int j = 0; j < 4; ++j) {
            int o = bB + j * 2048;
            intx4 lo = *(const intx4*)&Bs[o];
            intx4 hi = *(const intx4*)&Bs[o ^ 16];
            intx8 bg = __builtin_shufflevector(lo, hi, 0, 1, 2, 3, 4, 5, 6, 7);
#pragma unroll
            for (int i = 0; i < 4; ++i)
                acc[i][j] = __builtin_amdgcn_mfma_scale_f32_16x16x128_f8f6f4(
                    af[i], bg, acc[i][j], 0, 0,
                    0, 0x7f7f7f7f, 0, 0x7f7f7f7f);
        }
        __syncthreads();
    }

    // ---- epilogue: exp2 + fp8 pack via Ct bounce (aliases As+Bs) ----
    // (round-1 verified 16x16 geometry)
    unsigned char* Ct = smem;                   // 128*144 = 18432 <= 32768
    const float ec1  = 0.044194173824159216f * 1.44269504f;  // (1/sqrt c)*log2e
    const float mec2 = -5.77078016f;                          // -4*log2(e)
    float* ls = lsum + (size_t)bz * AREA;
#pragma unroll
    for (int jn = 0; jn < 4; ++jn) {
        const int nl = wn + jn * 16 + lr;       // local P row
        float rs = 0.f;
#pragma unroll
        for (int im = 0; im < 4; ++im) {
            float e0 = exp2f(fmaf(acc[im][jn][0], ec1, mec2));
            float e1 = exp2f(fmaf(acc[im][jn][1], ec1, mec2));
            float e2 = exp2f(fmaf(acc[im][jn][2], ec1, mec2));
            float e3 = exp2f(fmaf(acc[im][jn][3], ec1, mec2));
            rs += (e0 + e1) + (e2 + e3);
            int pk = __builtin_amdgcn_cvt_pk_fp8_f32(e0, e1, 0, false);
            pk = __builtin_amdgcn_cvt_pk_fp8_f32(e2, e3, pk, true);
            *(unsigned int*)&Ct[nl * 144 + wm + im * 16 + lq * 4] =
                (unsigned int)pk;
        }
        rs += __shfl_xor(rs, 16);
        rs += __shfl_xor(rs, 32);
        if (lq == 0) atomicAdd(&ls[n0 + nl], rs);
    }
    __syncthreads();
    // read back rows, store P row-major, 64B per thread
    const int row  = tid >> 1;
    const int half = (tid & 1) * 64;
    unsigned char* dstp = P + (size_t)bz * ((size_t)AREA * AREA) +
                          (size_t)(n0 + row) * AREA + m0 + half;
    const unsigned char* srcp = &Ct[row * 144 + half];
#pragma unroll
    for (int k = 0; k < 4; ++k)
        *(uint4*)(dstp + k * 16) = *(const uint4*)(srcp + k * 16);
}

// =====================================================================
// PV via MX-scaled fp8 MFMA 16x16x128 (scales=1.0), BKB=128 / 32 KB:
// same conflict-halving shape change as s_mx. K=4096 -> 32 K-iters.
// C[m][n] = (sum_k A[m][k]*B[n][k]) / lsum[m], bf16 out.
// =====================================================================
__global__ __launch_bounds__(256, 4) void pv_mx(
    const unsigned char* __restrict__ A, const unsigned char* __restrict__ B,
    unsigned short* __restrict__ C, const float* __restrict__ lsum,
    int M, int N, int K, int lda, int ldb, int ldc,
    long sA, long sB, long sC)
{
    constexpr int TBM = 128, TBN = 128, BKB = 128;
    __shared__ __align__(16) unsigned char As[TBM * BKB];   // 16 KB
    __shared__ __align__(16) unsigned char Bs[TBN * BKB];   // 16 KB

    const int tid  = threadIdx.x;
    const int wave = tid >> 6;
    const int lane = tid & 63;
    const int lr = lane & 15;
    const int lq = lane >> 4;
    const int wm = (wave >> 1) * 64;
    const int wn = (wave & 1) * 64;

    const int m0 = blockIdx.y * TBM;
    const int n0 = blockIdx.x * TBN;
    A += (size_t)blockIdx.z * sA + (size_t)m0 * lda;
    B += (size_t)blockIdx.z * sB + (size_t)n0 * ldb;

    // staging: 1024 16B-chunks per side, 8 chunks/row, XOR row&7 swizzle
    unsigned int aOff[4], bOff[4];
#pragma unroll
    for (int r = 0; r < 4; ++r) {
        int idx = r * 256 + tid;
        int row = idx >> 3;
        int scc = (idx & 7) ^ (row & 7);
        aOff[r] = (unsigned int)(row * lda + (scc << 4));
        bOff[r] = (unsigned int)(row * ldb + (scc << 4));
    }
    const int ra = wm + lr;
    const int rb = wn + lr;
    const int aB = ra * BKB + (((lq << 1) ^ (ra & 7)) << 4);
    const int bB = rb * BKB + (((lq << 1) ^ (rb & 7)) << 4);

    floatx4 acc[4][4];
#pragma unroll
    for (int i = 0; i < 4; ++i)
#pragma unroll
        for (int j = 0; j < 4; ++j) acc[i][j] = floatx4{0.f, 0.f, 0.f, 0.f};

    const char* Ab = (const char*)A;
    const char* Bb = (const char*)B;
    for (int k0 = 0; k0 < K; k0 += BKB) {
#pragma unroll
        for (int r = 0; r < 4; ++r)
            async_copy16(Ab + aOff[r], &As[(r * 256 + tid) * 16]);
#pragma unroll
        for (int r = 0; r < 4; ++r)
            async_copy16(Bb + bOff[r], &Bs[(r * 256 + tid) * 16]);
        Ab += BKB;
        Bb += BKB;
        __syncthreads();
        intx8 af[4];
#pragma unroll
        for (int i = 0; i < 4; ++i) {
            int o = aB + i * 2048;
            intx4 lo = *(const intx4*)&As[o];
            intx4 hi = *(const intx4*)&As[o ^ 16];
            af[i] = __builtin_shufflevector(lo, hi, 0, 1, 2, 3, 4, 5, 6, 7);
        }
#pragma unroll
        for (int j = 0; j < 4; ++j) {
            int o = bB + j * 2048;
            intx4 lo = *(const intx4*)&Bs[o];
            intx4 hi = *(const intx4*)&Bs[o ^ 16];
            intx8 bg = __builtin_shufflevector(lo, hi, 0, 1, 2, 3, 4, 5, 6, 7);
#pragma unroll
            for (int i = 0; i < 4; ++i)
                acc[i][j] = __builtin_amdgcn_mfma_scale_f32_16x16x128_f8f6f4(
                    af[i], bg, acc[i][j], 0, 0,
                    0, 0x7f7f7f7f, 0, 0x7f7f7f7f);
        }
        __syncthreads();
    }

    // epilogue: divide by lsum, bf16 out (round-1 verified 16x16 geometry)
    C += (size_t)blockIdx.z * sC;
    const float* ls = lsum + (size_t)blockIdx.z * M;
#pragma unroll
    for (int i = 0; i < 4; ++i) {
        const int mbase = m0 + wm + i * 16 + lq * 4;
        float inv4[4];
#pragma unroll
        for (int r = 0; r < 4; ++r) inv4[r] = 1.0f / ls[mbase + r];
#pragma unroll
        for (int j = 0; j < 4; ++j) {
            const int nn = n0 + wn + j * 16 + lr;
#pragma unroll
            for (int r = 0; r < 4; ++r) {
                size_t off = (size_t)(mbase + r) * ldc + nn;
                C[off] = f2bf(acc[i][j][r] * inv4[r]);
            }
        }
    }
}

// =====================================================================
// Prep: blocks [0,1024): GN stats partials; blocks [1024,2048): weight cvt
// =====================================================================
__global__ __launch_bounds__(256) void prep(
    const float* __restrict__ net, float2* __restrict__ part,
    const float* __restrict__ wq, const float* __restrict__ wk,
    const float* __restrict__ wv, const float* __restrict__ wo,
    const float* __restrict__ bq, const float* __restrict__ bk,
    unsigned short* __restrict__ wqkb, unsigned short* __restrict__ wvb,
    unsigned short* __restrict__ wob, float* __restrict__ bqk)
{
    if (blockIdx.x < 1024) {
        const int bg = blockIdx.x >> 3, q = blockIdx.x & 7;
        const float4* p = (const float4*)(net + (size_t)bg * 65536 + q * 8192);
        float s = 0.f, ss = 0.f;
#pragma unroll
        for (int i = 0; i < 8; ++i) {
            float4 v = p[threadIdx.x + i * 256];
            s  += v.x + v.y + v.z + v.w;
            ss += v.x * v.x + v.y * v.y + v.z * v.z + v.w * v.w;
        }
#pragma unroll
        for (int o = 32; o; o >>= 1) { s += __shfl_xor(s, o); ss += __shfl_xor(ss, o); }
        __shared__ float rs[4], rss[4];
        const int wave = threadIdx.x >> 6, lane = threadIdx.x & 63;
        if (lane == 0) { rs[wave] = s; rss[wave] = ss; }
        __syncthreads();
        if (threadIdx.x == 0) {
            float2 o;
            o.x = rs[0] + rs[1] + rs[2] + rs[3];
            o.y = rss[0] + rss[1] + rss[2] + rss[3];
            part[bg * 8 + q] = o;
        }
    } else {
        const int blk = blockIdx.x - 1024;
        const int i = blk * 256 + threadIdx.x;
        wqkb[i]          = f2bf(wq[i]);
        wqkb[262144 + i] = f2bf(wk[i]);
        wvb[i] = f2bf(wv[i]);
        wob[i] = f2bf(wo[i]);
        if (i < 512) { bqk[i] = bq[i]; bqk[512 + i] = bk[i]; }
    }
}

// =====================================================================
// Normalize + transpose (+inline stats finalize):
// net[b][c][a] fp32 -> xnT[b][a][c] bf16
// =====================================================================
__global__ __launch_bounds__(256) void gn_norm_t(
    const float* __restrict__ net, const float2* __restrict__ part,
    const float* __restrict__ gamma, const float* __restrict__ beta,
    unsigned short* __restrict__ xnT)
{
    __shared__ float tile[64][65];
    const int b = blockIdx.z, c0 = blockIdx.y * 64, a0 = blockIdx.x * 64;
    const int tq = threadIdx.x >> 6;
    const int tl = threadIdx.x & 63;
    float mu4[4], rs4[4];
#pragma unroll
    for (int gg = 0; gg < 4; ++gg) {
        int g = (c0 >> 4) + gg;
        float s = 0.f, ss = 0.f;
#pragma unroll
        for (int j = 0; j < 8; ++j) {
            float2 p = part[(b * NGRP + g) * 8 + j];
            s += p.x; ss += p.y;
        }
        float mu = s * (1.f / 65536.f);
        mu4[gg] = mu;
        rs4[gg] = rsqrtf(ss * (1.f / 65536.f) - mu * mu + 1e-6f);
    }
    const float* src = net + ((size_t)b * CCH + c0) * AREA + a0;
#pragma unroll
    for (int p = 0; p < 16; ++p) {
        int cr = p * 4 + tq;
        int c  = c0 + cr;
        int gg = cr >> 4;
        float x = src[(size_t)cr * AREA + tl];
        tile[cr][tl] = (x - mu4[gg]) * rs4[gg] * gamma[c] + beta[c];
    }
    __syncthreads();
    unsigned short* dst = xnT + ((size_t)b * AREA + a0) * CCH + c0;
#pragma unroll
    for (int p = 0; p < 16; ++p) {
        int ar = p * 4 + tq;
        dst[(size_t)ar * CCH + tl] = f2bf(tile[tl][ar]);
    }
}

// =====================================================================
// Host launch
// =====================================================================
extern "C" void kernel_launch(void* const* d_in, const int* in_sizes, int n_in,
                              void* d_out, int out_size, void* d_ws, size_t ws_size,
                              hipStream_t stream)
{
    (void)in_sizes; (void)n_in; (void)out_size; (void)ws_size;
    const float* net      = (const float*)d_in[0];
    const float* gn_scale = (const float*)d_in[1];
    const float* gn_bias  = (const float*)d_in[2];
    const float* wq = (const float*)d_in[3];
    const float* bq = (const float*)d_in[4];
    const float* wk = (const float*)d_in[5];
    const float* bk = (const float*)d_in[6];
    const float* wv = (const float*)d_in[7];
    const float* bv = (const float*)d_in[8];
    const float* wo = (const float*)d_in[9];
    const float* bo = (const float*)d_in[10];
    float* out = (float*)d_out;
    char* ws = (char*)d_ws;

    // workspace layout (bytes), high-water 140 MB:
    //   [       0,  2.0M) wqkb(1M) wvb(.5M) wob(.5M)
    //   [    2.0M,  2.2M) bqk, part, lsum
    //   [    4.0M, 20.0M) xnT [b][a][c] bf16
    //   [   20.0M, 36.0M) qkT [b][a][1024] fp8  (q | k per row; dead after S)
    //   [   52.0M, 60.0M) vB  [b][c][a] fp8
    //   [   60.0M, 76.0M) hT  [b][a][c] bf16
    //   [   76.0M,140.0M) Pall fp8 e4m3
    unsigned short* wqkb = (unsigned short*)(ws + 0);
    unsigned short* wvb  = (unsigned short*)(ws + 1048576);
    unsigned short* wob  = (unsigned short*)(ws + 1572864);
    float*          bqk  = (float*)(ws + 2097152);
    float2*         part = (float2*)(ws + 2105344);
    float*          lsum = (float*)(ws + 2121728);
    unsigned short* xnT  = (unsigned short*)(ws + 4194304);
    unsigned char*  qkT  = (unsigned char*)(ws + 20971520);
    unsigned char*  vB   = (unsigned char*)(ws + 54525952);
    unsigned short* hT   = (unsigned short*)(ws + 62914560);
    unsigned char*  Pall = (unsigned char*)(ws + 79691776);

    const long PB  = (long)AREA * AREA;              // P bytes per batch
    const long tb  = (long)TB;
    const long qks = (long)AREA * 1024;              // qkT batch stride (B)

    hipMemsetAsync(lsum, 0, 4 * AREA * sizeof(float), stream);
    prep<<<2048, 256, 0, stream>>>(net, part, wq, wk, wv, wo, bq, bk,
                                   wqkb, wvb, wob, bqk);
    gn_norm_t<<<dim3(64, 8, 4), 256, 0, stream>>>(net, part, gn_scale, gn_bias, xnT);

    // QK fused (fp8 out): qkT[b][a][n] = fp8(sum_c xnT[a][c]*wqk[n][c] + bqk[n])
    gemm_tn<128, 128, unsigned char, 2, false>
        <<<dim3(8, 32, 4), 256, 0, stream>>>(xnT, wqkb, qkT, bqk, nullptr,
            AREA, 1024, CCH, CCH, CCH, 1024, tb, 0, qks, 0, 1.0f);

    // S+exp MX fp8 16x16x128: Pall[b][i][j] = fp8(exp(s/sqrt(c)-4)); lsum rows.
    s_mx<<<dim3(32, 32, 4), 256, 0, stream>>>(qkT + 512, qkT, Pall, lsum);

    // V (fp8 out): vB[b][o][a] = fp8(sum_c wv[o][c]*xnT[a][c] + bv[o])
    gemm_tn<128, 128, unsigned char, 1, false>
        <<<dim3(32, 4, 4), 256, 0, stream>>>(wvb, xnT, vB, bv, nullptr,
            CCH, AREA, CCH, CCH, CCH, AREA, 0, tb, tb, 0, 1.0f);

    // PV (MX fp8 16x16x128, scales=1): hT[b][i][c] = (sum_j P_ij*v_cj)/l_i
    pv_mx<<<dim3(4, 32, 4), 256, 0, stream>>>(Pall, vB, hT, lsum,
            AREA, CCH, AREA, AREA, AREA, CCH, PB, tb, tb);

    // out[b][o][a] = net + bo[o] + sum_c wo[o][c]*hT[a][c]
    gemm_tn<128, 128, float, 1, true>
        <<<dim3(32, 4, 4), 256, 0, stream>>>(wob, hT, out, bo, net,
            CCH, AREA, CCH, CCH, CCH, AREA, 0, tb, tb, tb, 1.0f);
}

// Round 11
// 270.091 us; speedup vs baseline: 1.2777x; 1.2777x over previous
//
#include <hip/hip_runtime.h>
#include <cstdint>
#include <cstddef>

// ---------- types ----------
typedef __attribute__((ext_vector_type(8))) __bf16 bf16x8;
typedef __attribute__((ext_vector_type(4))) float floatx4;
typedef __attribute__((ext_vector_type(16))) float floatx16;
typedef __attribute__((ext_vector_type(4))) int intx4;
typedef __attribute__((ext_vector_type(8))) int intx8;

__device__ __forceinline__ unsigned short f2bf(float f) {
    unsigned int u = __float_as_uint(f);
    u += 0x7fffu + ((u >> 16) & 1u);      // RNE
    return (unsigned short)(u >> 16);
}

__device__ __forceinline__ void async_copy16(const void* gp, void* lp) {
    __builtin_amdgcn_global_load_lds(
        (__attribute__((address_space(1))) void*)gp,
        (__attribute__((address_space(3))) void*)lp,
        16, 0, 0);
}

// ---------- constants ----------
#define CCH 512
#define AREA 4096
#define NGRP 32
#define TB (AREA * CCH)        // per-batch tensor elements (2097152)

// =====================================================================
// TN GEMM (bf16 inputs): C[m][n] = alpha * sum_k A[m][k]*B[n][k]
// BIAS_MODE: 0 none, 1 per-m, 2 per-n. OutT: float | bf16 | fp8.
// 2-phase 128^2 structure, 3-4 blocks/CU.
// =====================================================================
template<int TBM, int TBN, typename OutT, int BIAS_MODE, bool RESID>
__global__ __launch_bounds__(256, 4) void gemm_tn(
    const unsigned short* __restrict__ A, const unsigned short* __restrict__ B,
    OutT* __restrict__ C, const float* __restrict__ bias,
    const float* __restrict__ resid,
    int M, int N, int K, int lda, int ldb, int ldc,
    long sA, long sB, long sC, long sR, float alpha)
{
    constexpr int BK = 64;
    constexpr int MT = TBM / 32;
    constexpr int NT = TBN / 32;
    constexpr int NAR = (TBM * BK) / (256 * 8);
    constexpr int NBR = (TBN * BK) / (256 * 8);
    __shared__ __align__(16) unsigned char smem[(TBM + TBN) * BK * 2];
    unsigned short* As = (unsigned short*)smem;
    unsigned short* Bs = (unsigned short*)(smem + TBM * BK * 2);

    const int tid  = threadIdx.x;
    const int wave = tid >> 6;
    const int lane = tid & 63;
    const int wm = (wave >> 1) * (MT * 16);
    const int wn = (wave & 1) * (NT * 16);
    const int lr = lane & 15;
    const int lq = lane >> 4;
    const int sw = lr & 7;

    const int m0 = blockIdx.y * TBM;
    const int n0 = blockIdx.x * TBN;
    A += (size_t)blockIdx.z * sA + (size_t)m0 * lda;
    B += (size_t)blockIdx.z * sB + (size_t)n0 * ldb;

    unsigned int aOff[NAR], bOff[NBR];
#pragma unroll
    for (int r = 0; r < NAR; ++r) {
        int idx = r * 256 + tid;
        int row = idx >> 3;
        int scc = (idx & 7) ^ (row & 7);
        aOff[r] = (unsigned int)(row * lda + (scc << 3)) * 2u;
    }
#pragma unroll
    for (int r = 0; r < NBR; ++r) {
        int idx = r * 256 + tid;
        int row = idx >> 3;
        int scc = (idx & 7) ^ (row & 7);
        bOff[r] = (unsigned int)(row * ldb + (scc << 3)) * 2u;
    }
    const int aBase = (wm + lr) * (BK * 2) + ((lq ^ sw) << 4);
    const int bBase = (wn + lr) * (BK * 2) + ((lq ^ sw) << 4);

    floatx4 acc[MT][NT];
#pragma unroll
    for (int i = 0; i < MT; ++i)
#pragma unroll
        for (int j = 0; j < NT; ++j) acc[i][j] = floatx4{0.f, 0.f, 0.f, 0.f};

    const char* Ab = (const char*)A;
    const char* Bb = (const char*)B;
    for (int k0 = 0; k0 < K; k0 += BK) {
#pragma unroll
        for (int r = 0; r < NAR; ++r)
            async_copy16(Ab + aOff[r], &As[(r * 256 + tid) * 8]);
#pragma unroll
        for (int r = 0; r < NBR; ++r)
            async_copy16(Bb + bOff[r], &Bs[(r * 256 + tid) * 8]);
        Ab += BK * 2;
        Bb += BK * 2;
        __syncthreads();
#pragma unroll
        for (int ks = 0; ks < BK / 32; ++ks) {
            bf16x8 af[MT], bg[NT];
#pragma unroll
            for (int i = 0; i < MT; ++i)
                af[i] = *(const bf16x8*)((const char*)As +
                        ((aBase ^ (ks << 6)) + i * (16 * BK * 2)));
#pragma unroll
            for (int j = 0; j < NT; ++j)
                bg[j] = *(const bf16x8*)((const char*)Bs +
                        ((bBase ^ (ks << 6)) + j * (16 * BK * 2)));
#pragma unroll
            for (int i = 0; i < MT; ++i)
#pragma unroll
                for (int j = 0; j < NT; ++j)
                    acc[i][j] = __builtin_amdgcn_mfma_f32_16x16x32_bf16(
                        af[i], bg[j], acc[i][j], 0, 0, 0);
        }
        __syncthreads();
    }

    // epilogue: C/D layout col=lane&15, row=(lane>>4)*4+reg
    C += (size_t)blockIdx.z * sC;
    if constexpr (RESID) resid += (size_t)blockIdx.z * sR;
    float bn[NT];
    if constexpr (BIAS_MODE == 2) {
#pragma unroll
        for (int j = 0; j < NT; ++j) bn[j] = bias[n0 + wn + j * 16 + lr];
    }
#pragma unroll
    for (int i = 0; i < MT; ++i) {
        const int mbase = m0 + wm + i * 16 + lq * 4;
        float bm4[4];
        if constexpr (BIAS_MODE == 1) {
#pragma unroll
            for (int r = 0; r < 4; ++r) bm4[r] = bias[mbase + r];
        }
#pragma unroll
        for (int j = 0; j < NT; ++j) {
            const int nn = n0 + wn + j * 16 + lr;
#pragma unroll
            for (int r = 0; r < 4; ++r) {
                float val = acc[i][j][r] * alpha;
                if constexpr (BIAS_MODE == 1) val += bm4[r];
                if constexpr (BIAS_MODE == 2) val += bn[j];
                size_t off = (size_t)(mbase + r) * ldc + nn;
                if constexpr (RESID) val += resid[off];
                if constexpr (sizeof(OutT) == 1) {
                    int pk = __builtin_amdgcn_cvt_pk_fp8_f32(val, val, 0, false);
                    C[off] = (OutT)(pk & 0xff);
                } else if constexpr (sizeof(OutT) == 2) {
                    C[off] = (OutT)f2bf(val);
                } else {
                    C[off] = val;
                }
            }
        }
    }
}

// =====================================================================
// S+exp via MX-scaled fp8 MFMA (scales=1.0), BKB=128 / 32 KB LDS.
// launch_bounds(256,4): VGPR budget 128 >= measured 64 -> NO SPILL.
// ((256,5) is a spill trap: occupancy steps at VGPR={64,128,256} only.
//  16x16x128 shape also spills: af[4]+acc exceed the 64-reg partition.
//  The ~5.7 "conflict" beats/read are the INHERENT b128 8-beat cost —
//  swizzle is already optimal; do not chase them.)
// A = K-vectors fp8 [4096][1024B ld] (+512 B col offset applied by host)
// B = Q-vectors fp8 [4096][1024B ld]
// P[b][i][j] = fp8(exp2(s*ec1 + mec2)); lsum[b][i] += fp32 row sums.
// Fragment algebra (HW-verified round 4/5/6): chunk c0 = kh*4 + l5*2,
// swizzled addr = row*128 + ((c0 ^ (row&7))<<4); partner at ^16; kh
// toggles ^(kh<<6).  C/D 32x32 layout: n-col = lane&31,
//   m-row = (reg&3) + 8*(reg>>2) + 4*(lane>>5).
// =====================================================================
__global__ __launch_bounds__(256, 4) void s_mx(
    const unsigned char* __restrict__ A, const unsigned char* __restrict__ B,
    unsigned char* __restrict__ P, float* __restrict__ lsum)
{
    constexpr int BKB = 128;
    __shared__ __align__(16) unsigned char smem[32768];
    unsigned char* As = smem;            // 16 KB
    unsigned char* Bs = smem + 16384;    // 16 KB

    const int tid  = threadIdx.x;
    const int wave = tid >> 6;
    const int lane = tid & 63;
    const int l5   = lane >> 5;
    const int lr32 = lane & 31;
    const int wm = (wave >> 1) * 64;   // m (P-col) half
    const int wn = (wave & 1) * 64;    // n (P-row) half

    const int m0 = blockIdx.y * 128;
    const int n0 = blockIdx.x * 128;
    const int bz = blockIdx.z;

    const unsigned char* Ap = A + (size_t)bz * ((size_t)AREA * 1024) +
                              (size_t)m0 * 1024;
    const unsigned char* Bp = B + (size_t)bz * ((size_t)AREA * 1024) +
                              (size_t)n0 * 1024;

    // staging: 1024 16B-chunks per side, 8 chunks/row, XOR row&7 swizzle
    unsigned int aOff[4];
#pragma unroll
    for (int r = 0; r < 4; ++r) {
        int idx = r * 256 + tid;
        int row = idx >> 3;
        int scc = (idx & 7) ^ (row & 7);
        aOff[r] = (unsigned int)(row * 1024 + (scc << 4));
    }
    const int ra = wm + lr32;
    const int rb = wn + lr32;
    const int aB = ra * BKB + (((l5 << 1) ^ (ra & 7)) << 4);
    const int bB = rb * BKB + (((l5 << 1) ^ (rb & 7)) << 4);

    floatx16 acc[2][2];    // [ia = m frag][jb = n frag]
#pragma unroll
    for (int i = 0; i < 2; ++i)
#pragma unroll
        for (int j = 0; j < 2; ++j)
#pragma unroll
            for (int r = 0; r < 16; ++r) acc[i][j][r] = 0.f;

    for (int k0 = 0; k0 < 512; k0 += BKB) {
#pragma unroll
        for (int r = 0; r < 4; ++r)
            async_copy16(Ap + k0 + aOff[r], &As[(r * 256 + tid) * 16]);
#pragma unroll
        for (int r = 0; r < 4; ++r)
            async_copy16(Bp + k0 + aOff[r], &Bs[(r * 256 + tid) * 16]);
        __syncthreads();
#pragma unroll
        for (int kh = 0; kh < 2; ++kh) {             // K=64 per step
            intx8 af[2], bg[2];
#pragma unroll
            for (int i = 0; i < 2; ++i) {
                int o = (aB + i * 32 * BKB) ^ (kh << 6);
                intx4 lo = *(const intx4*)&As[o];
                intx4 hi = *(const intx4*)&As[o ^ 16];
                af[i] = __builtin_shufflevector(lo, hi, 0, 1, 2, 3, 4, 5, 6, 7);
            }
#pragma unroll
            for (int j = 0; j < 2; ++j) {
                int o = (bB + j * 32 * BKB) ^ (kh << 6);
                intx4 lo = *(const intx4*)&Bs[o];
                intx4 hi = *(const intx4*)&Bs[o ^ 16];
                bg[j] = __builtin_shufflevector(lo, hi, 0, 1, 2, 3, 4, 5, 6, 7);
            }
#pragma unroll
            for (int i = 0; i < 2; ++i)
#pragma unroll
                for (int j = 0; j < 2; ++j)
                    acc[i][j] = __builtin_amdgcn_mfma_scale_f32_32x32x64_f8f6f4(
                        af[i], bg[j], acc[i][j], 0, 0,
                        0, 0x7f7f7f7f, 0, 0x7f7f7f7f);
        }
        __syncthreads();
    }

    // ---- epilogue: exp2 + fp8 pack via Ct bounce (aliases As+Bs) ----
    unsigned char* Ct = smem;                   // 128*144 = 18432 <= 32768
    const float ec1  = 0.044194173824159216f * 1.44269504f;  // (1/sqrt c)*log2e
    const float mec2 = -5.77078016f;                          // -4*log2(e)
    float* ls = lsum + (size_t)bz * AREA;
#pragma unroll
    for (int jb = 0; jb < 2; ++jb) {
        const int nl = wn + jb * 32 + lr32;     // local P row
        float rs = 0.f;
#pragma unroll
        for (int ia = 0; ia < 2; ++ia) {
#pragma unroll
            for (int g = 0; g < 4; ++g) {
                float e0 = exp2f(fmaf(acc[ia][jb][g * 4 + 0], ec1, mec2));
                float e1 = exp2f(fmaf(acc[ia][jb][g * 4 + 1], ec1, mec2));
                float e2 = exp2f(fmaf(acc[ia][jb][g * 4 + 2], ec1, mec2));
                float e3 = exp2f(fmaf(acc[ia][jb][g * 4 + 3], ec1, mec2));
                rs += (e0 + e1) + (e2 + e3);
                int pk = __builtin_amdgcn_cvt_pk_fp8_f32(e0, e1, 0, false);
                pk = __builtin_amdgcn_cvt_pk_fp8_f32(e2, e3, pk, true);
                *(unsigned int*)&Ct[nl * 144 + wm + ia * 32 + g * 8 + l5 * 4] =
                    (unsigned int)pk;
            }
        }
        rs += __shfl_xor(rs, 32);
        if (l5 == 0) atomicAdd(&ls[n0 + nl], rs);
    }
    __syncthreads();
    // read back rows, store P row-major, 64B per thread
    const int row  = tid >> 1;
    const int half = (tid & 1) * 64;
    unsigned char* dstp = P + (size_t)bz * ((size_t)AREA * AREA) +
                          (size_t)(n0 + row) * AREA + m0 + half;
    const unsigned char* srcp = &Ct[row * 144 + half];
#pragma unroll
    for (int k = 0; k < 4; ++k)
        *(uint4*)(dstp + k * 16) = *(const uint4*)(srcp + k * 16);
}

// =====================================================================
// PV via MX-scaled fp8 MFMA (scales = 1.0), BKB=256 / 64 KB LDS,
// launch_bounds(256,2) [round-4/5/6 proven config]:
// C[m][n] = (sum_k A[m][k]*B[n][k]) / lsum[m], bf16 out.
// =====================================================================
__global__ __launch_bounds__(256, 2) void pv_mx(
    const unsigned char* __restrict__ A, const unsigned char* __restrict__ B,
    unsigned short* __restrict__ C, const float* __restrict__ lsum,
    int M, int N, int K, int lda, int ldb, int ldc,
    long sA, long sB, long sC)
{
    constexpr int TBM = 128, TBN = 128, BKB = 256;
    __shared__ __align__(16) unsigned char As[TBM * BKB];   // 32 KB
    __shared__ __align__(16) unsigned char Bs[TBN * BKB];   // 32 KB

    const int tid  = threadIdx.x;
    const int wave = tid >> 6;
    const int lane = tid & 63;
    const int l5   = lane >> 5;
    const int lr32 = lane & 31;
    const int wm = (wave >> 1) * 64;
    const int wn = (wave & 1) * 64;

    const int m0 = blockIdx.y * TBM;
    const int n0 = blockIdx.x * TBN;
    A += (size_t)blockIdx.z * sA + (size_t)m0 * lda;
    B += (size_t)blockIdx.z * sB + (size_t)n0 * ldb;

    unsigned int aOff[8], bOff[8];
#pragma unroll
    for (int r = 0; r < 8; ++r) {
        int idx = r * 256 + tid;
        int row = idx >> 4;
        int scc = (idx & 15) ^ (row & 7);
        aOff[r] = (unsigned int)(row * lda + (scc << 4));
        bOff[r] = (unsigned int)(row * ldb + (scc << 4));
    }
    const int ra = wm + lr32;
    const int rb = wn + lr32;
    const int aB = ra * BKB + (((l5 << 1) ^ (ra & 7)) << 4);
    const int bB = rb * BKB + (((l5 << 1) ^ (rb & 7)) << 4);

    floatx16 acc[2][2];
#pragma unroll
    for (int i = 0; i < 2; ++i)
#pragma unroll
        for (int j = 0; j < 2; ++j)
#pragma unroll
            for (int r = 0; r < 16; ++r) acc[i][j][r] = 0.f;

    const char* Ab = (const char*)A;
    const char* Bb = (const char*)B;
    for (int k0 = 0; k0 < K; k0 += BKB) {
#pragma unroll
        for (int r = 0; r < 8; ++r)
            async_copy16(Ab + aOff[r], &As[(r * 256 + tid) * 16]);
#pragma unroll
        for (int r = 0; r < 8; ++r)
            async_copy16(Bb + bOff[r], &Bs[(r * 256 + tid) * 16]);
        Ab += BKB;
        Bb += BKB;
        __syncthreads();
#pragma unroll
        for (int kh = 0; kh < 4; ++kh) {             // K=64 per step
            intx8 af[2], bg[2];
#pragma unroll
            for (int i = 0; i < 2; ++i) {
                int o = (aB + i * 32 * BKB) ^ (kh << 6);
                intx4 lo = *(const intx4*)&As[o];
                intx4 hi = *(const intx4*)&As[o ^ 16];
                af[i] = __builtin_shufflevector(lo, hi, 0, 1, 2, 3, 4, 5, 6, 7);
            }
#pragma unroll
            for (int j = 0; j < 2; ++j) {
                int o = (bB + j * 32 * BKB) ^ (kh << 6);
                intx4 lo = *(const intx4*)&Bs[o];
                intx4 hi = *(const intx4*)&Bs[o ^ 16];
                bg[j] = __builtin_shufflevector(lo, hi, 0, 1, 2, 3, 4, 5, 6, 7);
            }
#pragma unroll
            for (int i = 0; i < 2; ++i)
#pragma unroll
                for (int j = 0; j < 2; ++j)
                    acc[i][j] = __builtin_amdgcn_mfma_scale_f32_32x32x64_f8f6f4(
                        af[i], bg[j], acc[i][j], 0, 0,
                        0, 0x7f7f7f7f, 0, 0x7f7f7f7f);
        }
        __syncthreads();
    }

    // epilogue: divide by lsum, bf16 out
    C += (size_t)blockIdx.z * sC;
    const float* ls = lsum + (size_t)blockIdx.z * M;
#pragma unroll
    for (int i = 0; i < 2; ++i) {
        const int mb = m0 + wm + i * 32 + 4 * l5;
        float inv16[16];
#pragma unroll
        for (int r = 0; r < 16; ++r)
            inv16[r] = 1.0f / ls[mb + (r & 3) + 8 * (r >> 2)];
#pragma unroll
        for (int j = 0; j < 2; ++j) {
            const int nn = n0 + wn + j * 32 + lr32;
#pragma unroll
            for (int r = 0; r < 16; ++r) {
                const int m = mb + (r & 3) + 8 * (r >> 2);
                C[(size_t)m * ldc + nn] = f2bf(acc[i][j][r] * inv16[r]);
            }
        }
    }
}

// =====================================================================
// Prep: blocks [0,1024): GN stats partials; blocks [1024,2048): weight cvt
// =====================================================================
__global__ __launch_bounds__(256) void prep(
    const float* __restrict__ net, float2* __restrict__ part,
    const float* __restrict__ wq, const float* __restrict__ wk,
    const float* __restrict__ wv, const float* __restrict__ wo,
    const float* __restrict__ bq, const float* __restrict__ bk,
    unsigned short* __restrict__ wqkb, unsigned short* __restrict__ wvb,
    unsigned short* __restrict__ wob, float* __restrict__ bqk)
{
    if (blockIdx.x < 1024) {
        const int bg = blockIdx.x >> 3, q = blockIdx.x & 7;
        const float4* p = (const float4*)(net + (size_t)bg * 65536 + q * 8192);
        float s = 0.f, ss = 0.f;
#pragma unroll
        for (int i = 0; i < 8; ++i) {
            float4 v = p[threadIdx.x + i * 256];
            s  += v.x + v.y + v.z + v.w;
            ss += v.x * v.x + v.y * v.y + v.z * v.z + v.w * v.w;
        }
#pragma unroll
        for (int o = 32; o; o >>= 1) { s += __shfl_xor(s, o); ss += __shfl_xor(ss, o); }
        __shared__ float rs[4], rss[4];
        const int wave = threadIdx.x >> 6, lane = threadIdx.x & 63;
        if (lane == 0) { rs[wave] = s; rss[wave] = ss; }
        __syncthreads();
        if (threadIdx.x == 0) {
            float2 o;
            o.x = rs[0] + rs[1] + rs[2] + rs[3];
            o.y = rss[0] + rss[1] + rss[2] + rss[3];
            part[bg * 8 + q] = o;
        }
    } else {
        const int blk = blockIdx.x - 1024;
        const int i = blk * 256 + threadIdx.x;
        wqkb[i]          = f2bf(wq[i]);
        wqkb[262144 + i] = f2bf(wk[i]);
        wvb[i] = f2bf(wv[i]);
        wob[i] = f2bf(wo[i]);
        if (i < 512) { bqk[i] = bq[i]; bqk[512 + i] = bk[i]; }
    }
}

// =====================================================================
// Normalize + transpose (+inline stats finalize):
// net[b][c][a] fp32 -> xnT[b][a][c] bf16
// =====================================================================
__global__ __launch_bounds__(256) void gn_norm_t(
    const float* __restrict__ net, const float2* __restrict__ part,
    const float* __restrict__ gamma, const float* __restrict__ beta,
    unsigned short* __restrict__ xnT)
{
    __shared__ float tile[64][65];
    const int b = blockIdx.z, c0 = blockIdx.y * 64, a0 = blockIdx.x * 64;
    const int tq = threadIdx.x >> 6;
    const int tl = threadIdx.x & 63;
    float mu4[4], rs4[4];
#pragma unroll
    for (int gg = 0; gg < 4; ++gg) {
        int g = (c0 >> 4) + gg;
        float s = 0.f, ss = 0.f;
#pragma unroll
        for (int j = 0; j < 8; ++j) {
            float2 p = part[(b * NGRP + g) * 8 + j];
            s += p.x; ss += p.y;
        }
        float mu = s * (1.f / 65536.f);
        mu4[gg] = mu;
        rs4[gg] = rsqrtf(ss * (1.f / 65536.f) - mu * mu + 1e-6f);
    }
    const float* src = net + ((size_t)b * CCH + c0) * AREA + a0;
#pragma unroll
    for (int p = 0; p < 16; ++p) {
        int cr = p * 4 + tq;
        int c  = c0 + cr;
        int gg = cr >> 4;
        float x = src[(size_t)cr * AREA + tl];
        tile[cr][tl] = (x - mu4[gg]) * rs4[gg] * gamma[c] + beta[c];
    }
    __syncthreads();
    unsigned short* dst = xnT + ((size_t)b * AREA + a0) * CCH + c0;
#pragma unroll
    for (int p = 0; p < 16; ++p) {
        int ar = p * 4 + tq;
        dst[(size_t)ar * CCH + tl] = f2bf(tile[tl][ar]);
    }
}

// =====================================================================
// Host launch
// =====================================================================
extern "C" void kernel_launch(void* const* d_in, const int* in_sizes, int n_in,
                              void* d_out, int out_size, void* d_ws, size_t ws_size,
                              hipStream_t stream)
{
    (void)in_sizes; (void)n_in; (void)out_size; (void)ws_size;
    const float* net      = (const float*)d_in[0];
    const float* gn_scale = (const float*)d_in[1];
    const float* gn_bias  = (const float*)d_in[2];
    const float* wq = (const float*)d_in[3];
    const float* bq = (const float*)d_in[4];
    const float* wk = (const float*)d_in[5];
    const float* bk = (const float*)d_in[6];
    const float* wv = (const float*)d_in[7];
    const float* bv = (const float*)d_in[8];
    const float* wo = (const float*)d_in[9];
    const float* bo = (const float*)d_in[10];
    float* out = (float*)d_out;
    char* ws = (char*)d_ws;

    // workspace layout (bytes), high-water 140 MB:
    //   [       0,  2.0M) wqkb(1M) wvb(.5M) wob(.5M)
    //   [    2.0M,  2.2M) bqk, part, lsum
    //   [    4.0M, 20.0M) xnT [b][a][c] bf16
    //   [   20.0M, 36.0M) qkT [b][a][1024] fp8  (q | k per row; dead after S)
    //   [   52.0M, 60.0M) vB  [b][c][a] fp8
    //   [   60.0M, 76.0M) hT  [b][a][c] bf16
    //   [   76.0M,140.0M) Pall fp8 e4m3
    unsigned short* wqkb = (unsigned short*)(ws + 0);
    unsigned short* wvb  = (unsigned short*)(ws + 1048576);
    unsigned short* wob  = (unsigned short*)(ws + 1572864);
    float*          bqk  = (float*)(ws + 2097152);
    float2*         part = (float2*)(ws + 2105344);
    float*          lsum = (float*)(ws + 2121728);
    unsigned short* xnT  = (unsigned short*)(ws + 4194304);
    unsigned char*  qkT  = (unsigned char*)(ws + 20971520);
    unsigned char*  vB   = (unsigned char*)(ws + 54525952);
    unsigned short* hT   = (unsigned short*)(ws + 62914560);
    unsigned char*  Pall = (unsigned char*)(ws + 79691776);

    const long PB  = (long)AREA * AREA;              // P bytes per batch
    const long tb  = (long)TB;
    const long qks = (long)AREA * 1024;              // qkT batch stride (B)

    hipMemsetAsync(lsum, 0, 4 * AREA * sizeof(float), stream);
    prep<<<2048, 256, 0, stream>>>(net, part, wq, wk, wv, wo, bq, bk,
                                   wqkb, wvb, wob, bqk);
    gn_norm_t<<<dim3(64, 8, 4), 256, 0, stream>>>(net, part, gn_scale, gn_bias, xnT);

    // QK fused (fp8 out): qkT[b][a][n] = fp8(sum_c xnT[a][c]*wqk[n][c] + bqk[n])
    gemm_tn<128, 128, unsigned char, 2, false>
        <<<dim3(8, 32, 4), 256, 0, stream>>>(xnT, wqkb, qkT, bqk, nullptr,
            AREA, 1024, CCH, CCH, CCH, 1024, tb, 0, qks, 0, 1.0f);

    // S+exp MX fp8 (BKB=128): Pall[b][i][j] = fp8(exp(s/sqrt(c) - 4)); lsum rows.
    s_mx<<<dim3(32, 32, 4), 256, 0, stream>>>(qkT + 512, qkT, Pall, lsum);

    // V (fp8 out): vB[b][o][a] = fp8(sum_c wv[o][c]*xnT[a][c] + bv[o])
    gemm_tn<128, 128, unsigned char, 1, false>
        <<<dim3(32, 4, 4), 256, 0, stream>>>(wvb, xnT, vB, bv, nullptr,
            CCH, AREA, CCH, CCH, CCH, AREA, 0, tb, tb, 0, 1.0f);

    // PV (MX fp8, scales=1, BKB=256): hT[b][i][c] = (sum_j P_ij * v_cj) / l_i
    pv_mx<<<dim3(4, 32, 4), 256, 0, stream>>>(Pall, vB, hT, lsum,
            AREA, CCH, AREA, AREA, AREA, CCH, PB, tb, tb);

    // out[b][o][a] = net + bo[o] + sum_c wo[o][c]*hT[a][c]
    gemm_tn<128, 128, float, 1, true>
        <<<dim3(32, 4, 4), 256, 0, stream>>>(wob, hT, out, bo, net,
            CCH, AREA, CCH, CCH, CCH, AREA, 0, tb, tb, tb, 1.0f);
}

// Round 12
// 263.135 us; speedup vs baseline: 1.3115x; 1.0264x over previous
//
#include <hip/hip_runtime.h>
#include <cstdint>
#include <cstddef>

// ---------- types ----------
typedef __attribute__((ext_vector_type(8))) __bf16 bf16x8;
typedef __attribute__((ext_vector_type(4))) float floatx4;
typedef __attribute__((ext_vector_type(16))) float floatx16;
typedef __attribute__((ext_vector_type(4))) int intx4;
typedef __attribute__((ext_vector_type(8))) int intx8;

__device__ __forceinline__ unsigned short f2bf(float f) {
    unsigned int u = __float_as_uint(f);
    u += 0x7fffu + ((u >> 16) & 1u);      // RNE
    return (unsigned short)(u >> 16);
}

__device__ __forceinline__ void async_copy16(const void* gp, void* lp) {
    __builtin_amdgcn_global_load_lds(
        (__attribute__((address_space(1))) void*)gp,
        (__attribute__((address_space(3))) void*)lp,
        16, 0, 0);
}

// ---------- constants ----------
#define CCH 512
#define AREA 4096
#define NGRP 32
#define TB (AREA * CCH)        // per-batch tensor elements (2097152)

// =====================================================================
// TN GEMM (bf16 inputs): C[m][n] = alpha * sum_k A[m][k]*B[n][k]
// BIAS_MODE: 0 none, 1 per-m, 2 per-n. OutT: float | bf16 | fp8.
// 2-phase 128^2 structure, 3-4 blocks/CU.
// =====================================================================
template<int TBM, int TBN, typename OutT, int BIAS_MODE, bool RESID>
__global__ __launch_bounds__(256, 4) void gemm_tn(
    const unsigned short* __restrict__ A, const unsigned short* __restrict__ B,
    OutT* __restrict__ C, const float* __restrict__ bias,
    const float* __restrict__ resid,
    int M, int N, int K, int lda, int ldb, int ldc,
    long sA, long sB, long sC, long sR, float alpha)
{
    constexpr int BK = 64;
    constexpr int MT = TBM / 32;
    constexpr int NT = TBN / 32;
    constexpr int NAR = (TBM * BK) / (256 * 8);
    constexpr int NBR = (TBN * BK) / (256 * 8);
    __shared__ __align__(16) unsigned char smem[(TBM + TBN) * BK * 2];
    unsigned short* As = (unsigned short*)smem;
    unsigned short* Bs = (unsigned short*)(smem + TBM * BK * 2);

    const int tid  = threadIdx.x;
    const int wave = tid >> 6;
    const int lane = tid & 63;
    const int wm = (wave >> 1) * (MT * 16);
    const int wn = (wave & 1) * (NT * 16);
    const int lr = lane & 15;
    const int lq = lane >> 4;
    const int sw = lr & 7;

    const int m0 = blockIdx.y * TBM;
    const int n0 = blockIdx.x * TBN;
    A += (size_t)blockIdx.z * sA + (size_t)m0 * lda;
    B += (size_t)blockIdx.z * sB + (size_t)n0 * ldb;

    unsigned int aOff[NAR], bOff[NBR];
#pragma unroll
    for (int r = 0; r < NAR; ++r) {
        int idx = r * 256 + tid;
        int row = idx >> 3;
        int scc = (idx & 7) ^ (row & 7);
        aOff[r] = (unsigned int)(row * lda + (scc << 3)) * 2u;
    }
#pragma unroll
    for (int r = 0; r < NBR; ++r) {
        int idx = r * 256 + tid;
        int row = idx >> 3;
        int scc = (idx & 7) ^ (row & 7);
        bOff[r] = (unsigned int)(row * ldb + (scc << 3)) * 2u;
    }
    const int aBase = (wm + lr) * (BK * 2) + ((lq ^ sw) << 4);
    const int bBase = (wn + lr) * (BK * 2) + ((lq ^ sw) << 4);

    floatx4 acc[MT][NT];
#pragma unroll
    for (int i = 0; i < MT; ++i)
#pragma unroll
        for (int j = 0; j < NT; ++j) acc[i][j] = floatx4{0.f, 0.f, 0.f, 0.f};

    const char* Ab = (const char*)A;
    const char* Bb = (const char*)B;
    for (int k0 = 0; k0 < K; k0 += BK) {
#pragma unroll
        for (int r = 0; r < NAR; ++r)
            async_copy16(Ab + aOff[r], &As[(r * 256 + tid) * 8]);
#pragma unroll
        for (int r = 0; r < NBR; ++r)
            async_copy16(Bb + bOff[r], &Bs[(r * 256 + tid) * 8]);
        Ab += BK * 2;
        Bb += BK * 2;
        __syncthreads();
#pragma unroll
        for (int ks = 0; ks < BK / 32; ++ks) {
            bf16x8 af[MT], bg[NT];
#pragma unroll
            for (int i = 0; i < MT; ++i)
                af[i] = *(const bf16x8*)((const char*)As +
                        ((aBase ^ (ks << 6)) + i * (16 * BK * 2)));
#pragma unroll
            for (int j = 0; j < NT; ++j)
                bg[j] = *(const bf16x8*)((const char*)Bs +
                        ((bBase ^ (ks << 6)) + j * (16 * BK * 2)));
#pragma unroll
            for (int i = 0; i < MT; ++i)
#pragma unroll
                for (int j = 0; j < NT; ++j)
                    acc[i][j] = __builtin_amdgcn_mfma_f32_16x16x32_bf16(
                        af[i], bg[j], acc[i][j], 0, 0, 0);
        }
        __syncthreads();
    }

    // epilogue: C/D layout col=lane&15, row=(lane>>4)*4+reg
    C += (size_t)blockIdx.z * sC;
    if constexpr (RESID) resid += (size_t)blockIdx.z * sR;
    float bn[NT];
    if constexpr (BIAS_MODE == 2) {
#pragma unroll
        for (int j = 0; j < NT; ++j) bn[j] = bias[n0 + wn + j * 16 + lr];
    }
#pragma unroll
    for (int i = 0; i < MT; ++i) {
        const int mbase = m0 + wm + i * 16 + lq * 4;
        float bm4[4];
        if constexpr (BIAS_MODE == 1) {
#pragma unroll
            for (int r = 0; r < 4; ++r) bm4[r] = bias[mbase + r];
        }
#pragma unroll
        for (int j = 0; j < NT; ++j) {
            const int nn = n0 + wn + j * 16 + lr;
#pragma unroll
            for (int r = 0; r < 4; ++r) {
                float val = acc[i][j][r] * alpha;
                if constexpr (BIAS_MODE == 1) val += bm4[r];
                if constexpr (BIAS_MODE == 2) val += bn[j];
                size_t off = (size_t)(mbase + r) * ldc + nn;
                if constexpr (RESID) val += resid[off];
                if constexpr (sizeof(OutT) == 1) {
                    int pk = __builtin_amdgcn_cvt_pk_fp8_f32(val, val, 0, false);
                    C[off] = (OutT)(pk & 0xff);
                } else if constexpr (sizeof(OutT) == 2) {
                    C[off] = (OutT)f2bf(val);
                } else {
                    C[off] = val;
                }
            }
        }
    }
}

// =====================================================================
// S+exp via MX-scaled fp8 MFMA (scales=1.0), BKB=128 / 32 KB LDS.
// launch_bounds(256,4): VGPR budget 128 >= measured 64 -> NO SPILL.
// ((256,5) is a spill trap: occupancy steps at VGPR={64,128,256} only.
//  16x16x128 shape also spills. The ~5.7 "conflict" beats/read are the
//  INHERENT b128 8-beat cost — swizzle already optimal.)
// A = K-vectors fp8 [4096][1024B ld] (+512 B col offset applied by host)
// B = Q-vectors fp8 [4096][1024B ld]
// P[b][i][j] = fp8(exp2(s*ec1 + mec2)); lsum[b][i] += fp32 row sums.
// Fragment algebra (HW-verified round 4/5/6): chunk c0 = kh*4 + l5*2,
// swizzled addr = row*128 + ((c0 ^ (row&7))<<4); partner at ^16; kh
// toggles ^(kh<<6).  C/D 32x32 layout: n-col = lane&31,
//   m-row = (reg&3) + 8*(reg>>2) + 4*(lane>>5).
// =====================================================================
__global__ __launch_bounds__(256, 4) void s_mx(
    const unsigned char* __restrict__ A, const unsigned char* __restrict__ B,
    unsigned char* __restrict__ P, float* __restrict__ lsum)
{
    constexpr int BKB = 128;
    __shared__ __align__(16) unsigned char smem[32768];
    unsigned char* As = smem;            // 16 KB
    unsigned char* Bs = smem + 16384;    // 16 KB

    const int tid  = threadIdx.x;
    const int wave = tid >> 6;
    const int lane = tid & 63;
    const int l5   = lane >> 5;
    const int lr32 = lane & 31;
    const int wm = (wave >> 1) * 64;   // m (P-col) half
    const int wn = (wave & 1) * 64;    // n (P-row) half

    const int m0 = blockIdx.y * 128;
    const int n0 = blockIdx.x * 128;
    const int bz = blockIdx.z;

    const unsigned char* Ap = A + (size_t)bz * ((size_t)AREA * 1024) +
                              (size_t)m0 * 1024;
    const unsigned char* Bp = B + (size_t)bz * ((size_t)AREA * 1024) +
                              (size_t)n0 * 1024;

    // staging: 1024 16B-chunks per side, 8 chunks/row, XOR row&7 swizzle
    unsigned int aOff[4];
#pragma unroll
    for (int r = 0; r < 4; ++r) {
        int idx = r * 256 + tid;
        int row = idx >> 3;
        int scc = (idx & 7) ^ (row & 7);
        aOff[r] = (unsigned int)(row * 1024 + (scc << 4));
    }
    const int ra = wm + lr32;
    const int rb = wn + lr32;
    const int aB = ra * BKB + (((l5 << 1) ^ (ra & 7)) << 4);
    const int bB = rb * BKB + (((l5 << 1) ^ (rb & 7)) << 4);

    floatx16 acc[2][2];    // [ia = m frag][jb = n frag]
#pragma unroll
    for (int i = 0; i < 2; ++i)
#pragma unroll
        for (int j = 0; j < 2; ++j)
#pragma unroll
            for (int r = 0; r < 16; ++r) acc[i][j][r] = 0.f;

    for (int k0 = 0; k0 < 512; k0 += BKB) {
#pragma unroll
        for (int r = 0; r < 4; ++r)
            async_copy16(Ap + k0 + aOff[r], &As[(r * 256 + tid) * 16]);
#pragma unroll
        for (int r = 0; r < 4; ++r)
            async_copy16(Bp + k0 + aOff[r], &Bs[(r * 256 + tid) * 16]);
        __syncthreads();
#pragma unroll
        for (int kh = 0; kh < 2; ++kh) {             // K=64 per step
            intx8 af[2], bg[2];
#pragma unroll
            for (int i = 0; i < 2; ++i) {
                int o = (aB + i * 32 * BKB) ^ (kh << 6);
                intx4 lo = *(const intx4*)&As[o];
                intx4 hi = *(const intx4*)&As[o ^ 16];
                af[i] = __builtin_shufflevector(lo, hi, 0, 1, 2, 3, 4, 5, 6, 7);
            }
#pragma unroll
            for (int j = 0; j < 2; ++j) {
                int o = (bB + j * 32 * BKB) ^ (kh << 6);
                intx4 lo = *(const intx4*)&Bs[o];
                intx4 hi = *(const intx4*)&Bs[o ^ 16];
                bg[j] = __builtin_shufflevector(lo, hi, 0, 1, 2, 3, 4, 5, 6, 7);
            }
#pragma unroll
            for (int i = 0; i < 2; ++i)
#pragma unroll
                for (int j = 0; j < 2; ++j)
                    acc[i][j] = __builtin_amdgcn_mfma_scale_f32_32x32x64_f8f6f4(
                        af[i], bg[j], acc[i][j], 0, 0,
                        0, 0x7f7f7f7f, 0, 0x7f7f7f7f);
        }
        __syncthreads();
    }

    // ---- epilogue: exp2 + fp8 pack via Ct bounce (aliases As+Bs) ----
    unsigned char* Ct = smem;                   // 128*144 = 18432 <= 32768
    const float ec1  = 0.044194173824159216f * 1.44269504f;  // (1/sqrt c)*log2e
    const float mec2 = -5.77078016f;                          // -4*log2(e)
    float* ls = lsum + (size_t)bz * AREA;
#pragma unroll
    for (int jb = 0; jb < 2; ++jb) {
        const int nl = wn + jb * 32 + lr32;     // local P row
        float rs = 0.f;
#pragma unroll
        for (int ia = 0; ia < 2; ++ia) {
#pragma unroll
            for (int g = 0; g < 4; ++g) {
                float e0 = exp2f(fmaf(acc[ia][jb][g * 4 + 0], ec1, mec2));
                float e1 = exp2f(fmaf(acc[ia][jb][g * 4 + 1], ec1, mec2));
                float e2 = exp2f(fmaf(acc[ia][jb][g * 4 + 2], ec1, mec2));
                float e3 = exp2f(fmaf(acc[ia][jb][g * 4 + 3], ec1, mec2));
                rs += (e0 + e1) + (e2 + e3);
                int pk = __builtin_amdgcn_cvt_pk_fp8_f32(e0, e1, 0, false);
                pk = __builtin_amdgcn_cvt_pk_fp8_f32(e2, e3, pk, true);
                *(unsigned int*)&Ct[nl * 144 + wm + ia * 32 + g * 8 + l5 * 4] =
                    (unsigned int)pk;
            }
        }
        rs += __shfl_xor(rs, 32);
        if (l5 == 0) atomicAdd(&ls[n0 + nl], rs);
    }
    __syncthreads();
    // read back rows, store P row-major, 64B per thread
    const int row  = tid >> 1;
    const int half = (tid & 1) * 64;
    unsigned char* dstp = P + (size_t)bz * ((size_t)AREA * AREA) +
                          (size_t)(n0 + row) * AREA + m0 + half;
    const unsigned char* srcp = &Ct[row * 144 + half];
#pragma unroll
    for (int k = 0; k < 4; ++k)
        *(uint4*)(dstp + k * 16) = *(const uint4*)(srcp + k * 16);
}

// =====================================================================
// PV via MX-scaled fp8 MFMA (scales = 1.0), BKB=256 / 64 KB LDS,
// launch_bounds(256,2) [round-4/5/6 proven config] + XCD-chunk swizzle:
// C[m][n] = (sum_k A[m][k]*B[n][k]) / lsum[m], bf16 out.
//
// XCD swizzle (T1): P (A operand) is 256 MB total — exceeds L3 — and
// each 512KB m-panel is read by the 4 n-tile blocks. Default dispatch
// round-robins those 4 siblings onto 4 DIFFERENT XCDs (private L2s) ->
// panel fetched 4x from HBM (~256 MB/dispatch). Remap so each XCD gets
// a contiguous 64-block chunk: siblings co-XCD + co-resident (2/CU x
// 32 CU = 64), k0-synced; panel slices + all 4 V-panels (2 MB) fit the
// 4 MB L2 -> P streams from HBM ~once. 512 % 8 == 0 -> bijective.
// =====================================================================
__global__ __launch_bounds__(256, 2) void pv_mx(
    const unsigned char* __restrict__ A, const unsigned char* __restrict__ B,
    unsigned short* __restrict__ C, const float* __restrict__ lsum,
    int M, int N, int K, int lda, int ldb, int ldc,
    long sA, long sB, long sC)
{
    constexpr int TBM = 128, TBN = 128, BKB = 256;
    __shared__ __align__(16) unsigned char As[TBM * BKB];   // 32 KB
    __shared__ __align__(16) unsigned char Bs[TBN * BKB];   // 32 KB

    const int tid  = threadIdx.x;
    const int wave = tid >> 6;
    const int lane = tid & 63;
    const int l5   = lane >> 5;
    const int lr32 = lane & 31;
    const int wm = (wave >> 1) * 64;
    const int wn = (wave & 1) * 64;

    // ---- XCD-chunk swizzle: hw flat id (x fastest) -> chunked wid ----
    // grid (4,32,4) = 512 blocks; chunk = 512/8 = 64 per XCD.
    const int f   = blockIdx.x + 4 * (blockIdx.y + 32 * blockIdx.z);
    const int wid = ((f & 7) << 6) + (f >> 3);
    const int bx  = wid & 3;           // n-tile (fastest: siblings co-XCD)
    const int by  = (wid >> 2) & 31;   // m-tile
    const int bz  = wid >> 7;          // batch

    const int m0 = by * TBM;
    const int n0 = bx * TBN;
    A += (size_t)bz * sA + (size_t)m0 * lda;
    B += (size_t)bz * sB + (size_t)n0 * ldb;

    unsigned int aOff[8], bOff[8];
#pragma unroll
    for (int r = 0; r < 8; ++r) {
        int idx = r * 256 + tid;
        int row = idx >> 4;
        int scc = (idx & 15) ^ (row & 7);
        aOff[r] = (unsigned int)(row * lda + (scc << 4));
        bOff[r] = (unsigned int)(row * ldb + (scc << 4));
    }
    const int ra = wm + lr32;
    const int rb = wn + lr32;
    const int aB = ra * BKB + (((l5 << 1) ^ (ra & 7)) << 4);
    const int bB = rb * BKB + (((l5 << 1) ^ (rb & 7)) << 4);

    floatx16 acc[2][2];
#pragma unroll
    for (int i = 0; i < 2; ++i)
#pragma unroll
        for (int j = 0; j < 2; ++j)
#pragma unroll
            for (int r = 0; r < 16; ++r) acc[i][j][r] = 0.f;

    const char* Ab = (const char*)A;
    const char* Bb = (const char*)B;
    for (int k0 = 0; k0 < K; k0 += BKB) {
#pragma unroll
        for (int r = 0; r < 8; ++r)
            async_copy16(Ab + aOff[r], &As[(r * 256 + tid) * 16]);
#pragma unroll
        for (int r = 0; r < 8; ++r)
            async_copy16(Bb + bOff[r], &Bs[(r * 256 + tid) * 16]);
        Ab += BKB;
        Bb += BKB;
        __syncthreads();
#pragma unroll
        for (int kh = 0; kh < 4; ++kh) {             // K=64 per step
            intx8 af[2], bg[2];
#pragma unroll
            for (int i = 0; i < 2; ++i) {
                int o = (aB + i * 32 * BKB) ^ (kh << 6);
                intx4 lo = *(const intx4*)&As[o];
                intx4 hi = *(const intx4*)&As[o ^ 16];
                af[i] = __builtin_shufflevector(lo, hi, 0, 1, 2, 3, 4, 5, 6, 7);
            }
#pragma unroll
            for (int j = 0; j < 2; ++j) {
                int o = (bB + j * 32 * BKB) ^ (kh << 6);
                intx4 lo = *(const intx4*)&Bs[o];
                intx4 hi = *(const intx4*)&Bs[o ^ 16];
                bg[j] = __builtin_shufflevector(lo, hi, 0, 1, 2, 3, 4, 5, 6, 7);
            }
#pragma unroll
            for (int i = 0; i < 2; ++i)
#pragma unroll
                for (int j = 0; j < 2; ++j)
                    acc[i][j] = __builtin_amdgcn_mfma_scale_f32_32x32x64_f8f6f4(
                        af[i], bg[j], acc[i][j], 0, 0,
                        0, 0x7f7f7f7f, 0, 0x7f7f7f7f);
        }
        __syncthreads();
    }

    // epilogue: divide by lsum, bf16 out
    C += (size_t)bz * sC;
    const float* ls = lsum + (size_t)bz * M;
#pragma unroll
    for (int i = 0; i < 2; ++i) {
        const int mb = m0 + wm + i * 32 + 4 * l5;
        float inv16[16];
#pragma unroll
        for (int r = 0; r < 16; ++r)
            inv16[r] = 1.0f / ls[mb + (r & 3) + 8 * (r >> 2)];
#pragma unroll
        for (int j = 0; j < 2; ++j) {
            const int nn = n0 + wn + j * 32 + lr32;
#pragma unroll
            for (int r = 0; r < 16; ++r) {
                const int m = mb + (r & 3) + 8 * (r >> 2);
                C[(size_t)m * ldc + nn] = f2bf(acc[i][j][r] * inv16[r]);
            }
        }
    }
}

// =====================================================================
// Prep: blocks [0,1024): GN stats partials; blocks [1024,2048): weight cvt
// =====================================================================
__global__ __launch_bounds__(256) void prep(
    const float* __restrict__ net, float2* __restrict__ part,
    const float* __restrict__ wq, const float* __restrict__ wk,
    const float* __restrict__ wv, const float* __restrict__ wo,
    const float* __restrict__ bq, const float* __restrict__ bk,
    unsigned short* __restrict__ wqkb, unsigned short* __restrict__ wvb,
    unsigned short* __restrict__ wob, float* __restrict__ bqk)
{
    if (blockIdx.x < 1024) {
        const int bg = blockIdx.x >> 3, q = blockIdx.x & 7;
        const float4* p = (const float4*)(net + (size_t)bg * 65536 + q * 8192);
        float s = 0.f, ss = 0.f;
#pragma unroll
        for (int i = 0; i < 8; ++i) {
            float4 v = p[threadIdx.x + i * 256];
            s  += v.x + v.y + v.z + v.w;
            ss += v.x * v.x + v.y * v.y + v.z * v.z + v.w * v.w;
        }
#pragma unroll
        for (int o = 32; o; o >>= 1) { s += __shfl_xor(s, o); ss += __shfl_xor(ss, o); }
        __shared__ float rs[4], rss[4];
        const int wave = threadIdx.x >> 6, lane = threadIdx.x & 63;
        if (lane == 0) { rs[wave] = s; rss[wave] = ss; }
        __syncthreads();
        if (threadIdx.x == 0) {
            float2 o;
            o.x = rs[0] + rs[1] + rs[2] + rs[3];
            o.y = rss[0] + rss[1] + rss[2] + rss[3];
            part[bg * 8 + q] = o;
        }
    } else {
        const int blk = blockIdx.x - 1024;
        const int i = blk * 256 + threadIdx.x;
        wqkb[i]          = f2bf(wq[i]);
        wqkb[262144 + i] = f2bf(wk[i]);
        wvb[i] = f2bf(wv[i]);
        wob[i] = f2bf(wo[i]);
        if (i < 512) { bqk[i] = bq[i]; bqk[512 + i] = bk[i]; }
    }
}

// =====================================================================
// Normalize + transpose (+inline stats finalize):
// net[b][c][a] fp32 -> xnT[b][a][c] bf16
// =====================================================================
__global__ __launch_bounds__(256) void gn_norm_t(
    const float* __restrict__ net, const float2* __restrict__ part,
    const float* __restrict__ gamma, const float* __restrict__ beta,
    unsigned short* __restrict__ xnT)
{
    __shared__ float tile[64][65];
    const int b = blockIdx.z, c0 = blockIdx.y * 64, a0 = blockIdx.x * 64;
    const int tq = threadIdx.x >> 6;
    const int tl = threadIdx.x & 63;
    float mu4[4], rs4[4];
#pragma unroll
    for (int gg = 0; gg < 4; ++gg) {
        int g = (c0 >> 4) + gg;
        float s = 0.f, ss = 0.f;
#pragma unroll
        for (int j = 0; j < 8; ++j) {
            float2 p = part[(b * NGRP + g) * 8 + j];
            s += p.x; ss += p.y;
        }
        float mu = s * (1.f / 65536.f);
        mu4[gg] = mu;
        rs4[gg] = rsqrtf(ss * (1.f / 65536.f) - mu * mu + 1e-6f);
    }
    const float* src = net + ((size_t)b * CCH + c0) * AREA + a0;
#pragma unroll
    for (int p = 0; p < 16; ++p) {
        int cr = p * 4 + tq;
        int c  = c0 + cr;
        int gg = cr >> 4;
        float x = src[(size_t)cr * AREA + tl];
        tile[cr][tl] = (x - mu4[gg]) * rs4[gg] * gamma[c] + beta[c];
    }
    __syncthreads();
    unsigned short* dst = xnT + ((size_t)b * AREA + a0) * CCH + c0;
#pragma unroll
    for (int p = 0; p < 16; ++p) {
        int ar = p * 4 + tq;
        dst[(size_t)ar * CCH + tl] = f2bf(tile[tl][ar]);
    }
}

// =====================================================================
// Host launch
// =====================================================================
extern "C" void kernel_launch(void* const* d_in, const int* in_sizes, int n_in,
                              void* d_out, int out_size, void* d_ws, size_t ws_size,
                              hipStream_t stream)
{
    (void)in_sizes; (void)n_in; (void)out_size; (void)ws_size;
    const float* net      = (const float*)d_in[0];
    const float* gn_scale = (const float*)d_in[1];
    const float* gn_bias  = (const float*)d_in[2];
    const float* wq = (const float*)d_in[3];
    const float* bq = (const float*)d_in[4];
    const float* wk = (const float*)d_in[5];
    const float* bk = (const float*)d_in[6];
    const float* wv = (const float*)d_in[7];
    const float* bv = (const float*)d_in[8];
    const float* wo = (const float*)d_in[9];
    const float* bo = (const float*)d_in[10];
    float* out = (float*)d_out;
    char* ws = (char*)d_ws;

    // workspace layout (bytes), high-water 140 MB:
    //   [       0,  2.0M) wqkb(1M) wvb(.5M) wob(.5M)
    //   [    2.0M,  2.2M) bqk, part, lsum
    //   [    4.0M, 20.0M) xnT [b][a][c] bf16
    //   [   20.0M, 36.0M) qkT [b][a][1024] fp8  (q | k per row; dead after S)
    //   [   52.0M, 60.0M) vB  [b][c][a] fp8
    //   [   60.0M, 76.0M) hT  [b][a][c] bf16
    //   [   76.0M,140.0M) Pall fp8 e4m3
    unsigned short* wqkb = (unsigned short*)(ws + 0);
    unsigned short* wvb  = (unsigned short*)(ws + 1048576);
    unsigned short* wob  = (unsigned short*)(ws + 1572864);
    float*          bqk  = (float*)(ws + 2097152);
    float2*         part = (float2*)(ws + 2105344);
    float*          lsum = (float*)(ws + 2121728);
    unsigned short* xnT  = (unsigned short*)(ws + 4194304);
    unsigned char*  qkT  = (unsigned char*)(ws + 20971520);
    unsigned char*  vB   = (unsigned char*)(ws + 54525952);
    unsigned short* hT   = (unsigned short*)(ws + 62914560);
    unsigned char*  Pall = (unsigned char*)(ws + 79691776);

    const long PB  = (long)AREA * AREA;              // P bytes per batch
    const long tb  = (long)TB;
    const long qks = (long)AREA * 1024;              // qkT batch stride (B)

    hipMemsetAsync(lsum, 0, 4 * AREA * sizeof(float), stream);
    prep<<<2048, 256, 0, stream>>>(net, part, wq, wk, wv, wo, bq, bk,
                                   wqkb, wvb, wob, bqk);
    gn_norm_t<<<dim3(64, 8, 4), 256, 0, stream>>>(net, part, gn_scale, gn_bias, xnT);

    // QK fused (fp8 out): qkT[b][a][n] = fp8(sum_c xnT[a][c]*wqk[n][c] + bqk[n])
    gemm_tn<128, 128, unsigned char, 2, false>
        <<<dim3(8, 32, 4), 256, 0, stream>>>(xnT, wqkb, qkT, bqk, nullptr,
            AREA, 1024, CCH, CCH, CCH, 1024, tb, 0, qks, 0, 1.0f);

    // S+exp MX fp8 (BKB=128): Pall[b][i][j] = fp8(exp(s/sqrt(c) - 4)); lsum rows.
    s_mx<<<dim3(32, 32, 4), 256, 0, stream>>>(qkT + 512, qkT, Pall, lsum);

    // V (fp8 out): vB[b][o][a] = fp8(sum_c wv[o][c]*xnT[a][c] + bv[o])
    gemm_tn<128, 128, unsigned char, 1, false>
        <<<dim3(32, 4, 4), 256, 0, stream>>>(wvb, xnT, vB, bv, nullptr,
            CCH, AREA, CCH, CCH, CCH, AREA, 0, tb, tb, 0, 1.0f);

    // PV (MX fp8, scales=1, BKB=256, XCD-swizzled): hT = (P @ V^T) / lsum
    pv_mx<<<dim3(4, 32, 4), 256, 0, stream>>>(Pall, vB, hT, lsum,
            AREA, CCH, AREA, AREA, AREA, CCH, PB, tb, tb);

    // out[b][o][a] = net + bo[o] + sum_c wo[o][c]*hT[a][c]
    gemm_tn<128, 128, float, 1, true>
        <<<dim3(32, 4, 4), 256, 0, stream>>>(wob, hT, out, bo, net,
            CCH, AREA, CCH, CCH, CCH, AREA, 0, tb, tb, tb, 1.0f);
}

// Round 13
// 237.943 us; speedup vs baseline: 1.4504x; 1.1059x over previous
//
#include <hip/hip_runtime.h>
#include <cstdint>
#include <cstddef>

// ---------- types ----------
typedef __attribute__((ext_vector_type(8))) __bf16 bf16x8;
typedef __attribute__((ext_vector_type(4))) float floatx4;
typedef __attribute__((ext_vector_type(16))) float floatx16;
typedef __attribute__((ext_vector_type(4))) int intx4;
typedef __attribute__((ext_vector_type(8))) int intx8;

__device__ __forceinline__ unsigned short f2bf(float f) {
    unsigned int u = __float_as_uint(f);
    u += 0x7fffu + ((u >> 16) & 1u);      // RNE
    return (unsigned short)(u >> 16);
}

__device__ __forceinline__ unsigned char f2f8(float f) {
    int pk = __builtin_amdgcn_cvt_pk_fp8_f32(f, f, 0, false);
    return (unsigned char)(pk & 0xff);
}

__device__ __forceinline__ void async_copy16(const void* gp, void* lp) {
    __builtin_amdgcn_global_load_lds(
        (__attribute__((address_space(1))) void*)gp,
        (__attribute__((address_space(3))) void*)lp,
        16, 0, 0);
}

// ---------- constants ----------
#define CCH 512
#define AREA 4096
#define NGRP 32
#define TB (AREA * CCH)        // per-batch tensor elements (2097152)

// =====================================================================
// TN GEMM (bf16 inputs): C[m][n] = alpha * sum_k A[m][k]*B[n][k]
// BIAS_MODE: 0 none, 1 per-m, 2 per-n. OutT: float | bf16 | fp8.
// 2-phase 128^2 structure, 3-4 blocks/CU.  (Used only for WO now.)
// =====================================================================
template<int TBM, int TBN, typename OutT, int BIAS_MODE, bool RESID>
__global__ __launch_bounds__(256, 4) void gemm_tn(
    const unsigned short* __restrict__ A, const unsigned short* __restrict__ B,
    OutT* __restrict__ C, const float* __restrict__ bias,
    const float* __restrict__ resid,
    int M, int N, int K, int lda, int ldb, int ldc,
    long sA, long sB, long sC, long sR, float alpha)
{
    constexpr int BK = 64;
    constexpr int MT = TBM / 32;
    constexpr int NT = TBN / 32;
    constexpr int NAR = (TBM * BK) / (256 * 8);
    constexpr int NBR = (TBN * BK) / (256 * 8);
    __shared__ __align__(16) unsigned char smem[(TBM + TBN) * BK * 2];
    unsigned short* As = (unsigned short*)smem;
    unsigned short* Bs = (unsigned short*)(smem + TBM * BK * 2);

    const int tid  = threadIdx.x;
    const int wave = tid >> 6;
    const int lane = tid & 63;
    const int wm = (wave >> 1) * (MT * 16);
    const int wn = (wave & 1) * (NT * 16);
    const int lr = lane & 15;
    const int lq = lane >> 4;
    const int sw = lr & 7;

    const int m0 = blockIdx.y * TBM;
    const int n0 = blockIdx.x * TBN;
    A += (size_t)blockIdx.z * sA + (size_t)m0 * lda;
    B += (size_t)blockIdx.z * sB + (size_t)n0 * ldb;

    unsigned int aOff[NAR], bOff[NBR];
#pragma unroll
    for (int r = 0; r < NAR; ++r) {
        int idx = r * 256 + tid;
        int row = idx >> 3;
        int scc = (idx & 7) ^ (row & 7);
        aOff[r] = (unsigned int)(row * lda + (scc << 3)) * 2u;
    }
#pragma unroll
    for (int r = 0; r < NBR; ++r) {
        int idx = r * 256 + tid;
        int row = idx >> 3;
        int scc = (idx & 7) ^ (row & 7);
        bOff[r] = (unsigned int)(row * ldb + (scc << 3)) * 2u;
    }
    const int aBase = (wm + lr) * (BK * 2) + ((lq ^ sw) << 4);
    const int bBase = (wn + lr) * (BK * 2) + ((lq ^ sw) << 4);

    floatx4 acc[MT][NT];
#pragma unroll
    for (int i = 0; i < MT; ++i)
#pragma unroll
        for (int j = 0; j < NT; ++j) acc[i][j] = floatx4{0.f, 0.f, 0.f, 0.f};

    const char* Ab = (const char*)A;
    const char* Bb = (const char*)B;
    for (int k0 = 0; k0 < K; k0 += BK) {
#pragma unroll
        for (int r = 0; r < NAR; ++r)
            async_copy16(Ab + aOff[r], &As[(r * 256 + tid) * 8]);
#pragma unroll
        for (int r = 0; r < NBR; ++r)
            async_copy16(Bb + bOff[r], &Bs[(r * 256 + tid) * 8]);
        Ab += BK * 2;
        Bb += BK * 2;
        __syncthreads();
#pragma unroll
        for (int ks = 0; ks < BK / 32; ++ks) {
            bf16x8 af[MT], bg[NT];
#pragma unroll
            for (int i = 0; i < MT; ++i)
                af[i] = *(const bf16x8*)((const char*)As +
                        ((aBase ^ (ks << 6)) + i * (16 * BK * 2)));
#pragma unroll
            for (int j = 0; j < NT; ++j)
                bg[j] = *(const bf16x8*)((const char*)Bs +
                        ((bBase ^ (ks << 6)) + j * (16 * BK * 2)));
#pragma unroll
            for (int i = 0; i < MT; ++i)
#pragma unroll
                for (int j = 0; j < NT; ++j)
                    acc[i][j] = __builtin_amdgcn_mfma_f32_16x16x32_bf16(
                        af[i], bg[j], acc[i][j], 0, 0, 0);
        }
        __syncthreads();
    }

    // epilogue: C/D layout col=lane&15, row=(lane>>4)*4+reg
    C += (size_t)blockIdx.z * sC;
    if constexpr (RESID) resid += (size_t)blockIdx.z * sR;
    float bn[NT];
    if constexpr (BIAS_MODE == 2) {
#pragma unroll
        for (int j = 0; j < NT; ++j) bn[j] = bias[n0 + wn + j * 16 + lr];
    }
#pragma unroll
    for (int i = 0; i < MT; ++i) {
        const int mbase = m0 + wm + i * 16 + lq * 4;
        float bm4[4];
        if constexpr (BIAS_MODE == 1) {
#pragma unroll
            for (int r = 0; r < 4; ++r) bm4[r] = bias[mbase + r];
        }
#pragma unroll
        for (int j = 0; j < NT; ++j) {
            const int nn = n0 + wn + j * 16 + lr;
#pragma unroll
            for (int r = 0; r < 4; ++r) {
                float val = acc[i][j][r] * alpha;
                if constexpr (BIAS_MODE == 1) val += bm4[r];
                if constexpr (BIAS_MODE == 2) val += bn[j];
                size_t off = (size_t)(mbase + r) * ldc + nn;
                if constexpr (RESID) val += resid[off];
                if constexpr (sizeof(OutT) == 1) {
                    C[off] = (OutT)f2f8(val);
                } else if constexpr (sizeof(OutT) == 2) {
                    C[off] = (OutT)f2bf(val);
                } else {
                    C[off] = val;
                }
            }
        }
    }
}

// =====================================================================
// Generic MX fp8 TN GEMM with bias (clone of s_mx K-loop + pv_mx
// epilogue geometry — all HW-verified): C[m][n] = sum_k A[m][k]*B[n][k]
// + bias, fp8 out.  BIAS_MODE: 1 per-m, 2 per-n.
// BKB=128 / 32 KB LDS / (256,4) — proven no-spill geometry (VGPR 64).
// =====================================================================
template<int BIAS_MODE>
__global__ __launch_bounds__(256, 4) void gemm_mx(
    const unsigned char* __restrict__ A, const unsigned char* __restrict__ B,
    unsigned char* __restrict__ C, const float* __restrict__ bias,
    int M, int N, int K, int lda, int ldb, int ldc,
    long sA, long sB, long sC)
{
    constexpr int BKB = 128;
    __shared__ __align__(16) unsigned char smem[32768];
    unsigned char* As = smem;            // 16 KB
    unsigned char* Bs = smem + 16384;    // 16 KB

    const int tid  = threadIdx.x;
    const int wave = tid >> 6;
    const int lane = tid & 63;
    const int l5   = lane >> 5;
    const int lr32 = lane & 31;
    const int wm = (wave >> 1) * 64;
    const int wn = (wave & 1) * 64;

    const int m0 = blockIdx.y * 128;
    const int n0 = blockIdx.x * 128;
    A += (size_t)blockIdx.z * sA + (size_t)m0 * lda;
    B += (size_t)blockIdx.z * sB + (size_t)n0 * ldb;

    // staging: 1024 16B-chunks per side, 8 chunks/row, XOR row&7 swizzle
    unsigned int aOff[4], bOff[4];
#pragma unroll
    for (int r = 0; r < 4; ++r) {
        int idx = r * 256 + tid;
        int row = idx >> 3;
        int scc = (idx & 7) ^ (row & 7);
        aOff[r] = (unsigned int)(row * lda + (scc << 4));
        bOff[r] = (unsigned int)(row * ldb + (scc << 4));
    }
    const int ra = wm + lr32;
    const int rb = wn + lr32;
    const int aB = ra * BKB + (((l5 << 1) ^ (ra & 7)) << 4);
    const int bB = rb * BKB + (((l5 << 1) ^ (rb & 7)) << 4);

    floatx16 acc[2][2];
#pragma unroll
    for (int i = 0; i < 2; ++i)
#pragma unroll
        for (int j = 0; j < 2; ++j)
#pragma unroll
            for (int r = 0; r < 16; ++r) acc[i][j][r] = 0.f;

    const char* Ab = (const char*)A;
    const char* Bb = (const char*)B;
    for (int k0 = 0; k0 < K; k0 += BKB) {
#pragma unroll
        for (int r = 0; r < 4; ++r)
            async_copy16(Ab + aOff[r], &As[(r * 256 + tid) * 16]);
#pragma unroll
        for (int r = 0; r < 4; ++r)
            async_copy16(Bb + bOff[r], &Bs[(r * 256 + tid) * 16]);
        Ab += BKB;
        Bb += BKB;
        __syncthreads();
#pragma unroll
        for (int kh = 0; kh < 2; ++kh) {             // K=64 per step
            intx8 af[2], bg[2];
#pragma unroll
            for (int i = 0; i < 2; ++i) {
                int o = (aB + i * 32 * BKB) ^ (kh << 6);
                intx4 lo = *(const intx4*)&As[o];
                intx4 hi = *(const intx4*)&As[o ^ 16];
                af[i] = __builtin_shufflevector(lo, hi, 0, 1, 2, 3, 4, 5, 6, 7);
            }
#pragma unroll
            for (int j = 0; j < 2; ++j) {
                int o = (bB + j * 32 * BKB) ^ (kh << 6);
                intx4 lo = *(const intx4*)&Bs[o];
                intx4 hi = *(const intx4*)&Bs[o ^ 16];
                bg[j] = __builtin_shufflevector(lo, hi, 0, 1, 2, 3, 4, 5, 6, 7);
            }
#pragma unroll
            for (int i = 0; i < 2; ++i)
#pragma unroll
                for (int j = 0; j < 2; ++j)
                    acc[i][j] = __builtin_amdgcn_mfma_scale_f32_32x32x64_f8f6f4(
                        af[i], bg[j], acc[i][j], 0, 0,
                        0, 0x7f7f7f7f, 0, 0x7f7f7f7f);
        }
        __syncthreads();
    }

    // epilogue: C/D 32x32 (n-col = lane&31, m-row = (r&3)+8*(r>>2)+4*l5)
    C += (size_t)blockIdx.z * sC;
    float bn[2];
    if constexpr (BIAS_MODE == 2) {
#pragma unroll
        for (int j = 0; j < 2; ++j) bn[j] = bias[n0 + wn + j * 32 + lr32];
    }
#pragma unroll
    for (int i = 0; i < 2; ++i) {
        const int mb = m0 + wm + i * 32 + 4 * l5;
        float bm16[16];
        if constexpr (BIAS_MODE == 1) {
#pragma unroll
            for (int r = 0; r < 16; ++r)
                bm16[r] = bias[mb + (r & 3) + 8 * (r >> 2)];
        }
#pragma unroll
        for (int j = 0; j < 2; ++j) {
            const int nn = n0 + wn + j * 32 + lr32;
#pragma unroll
            for (int r = 0; r < 16; ++r) {
                const int m = mb + (r & 3) + 8 * (r >> 2);
                float val = acc[i][j][r];
                if constexpr (BIAS_MODE == 1) val += bm16[r];
                if constexpr (BIAS_MODE == 2) val += bn[j];
                C[(size_t)m * ldc + nn] = f2f8(val);
            }
        }
    }
}

// =====================================================================
// S+exp via MX-scaled fp8 MFMA (scales=1.0), BKB=128 / 32 KB LDS.
// launch_bounds(256,4): VGPR 64, no spill.  [champion config]
// =====================================================================
__global__ __launch_bounds__(256, 4) void s_mx(
    const unsigned char* __restrict__ A, const unsigned char* __restrict__ B,
    unsigned char* __restrict__ P, float* __restrict__ lsum)
{
    constexpr int BKB = 128;
    __shared__ __align__(16) unsigned char smem[32768];
    unsigned char* As = smem;            // 16 KB
    unsigned char* Bs = smem + 16384;    // 16 KB

    const int tid  = threadIdx.x;
    const int wave = tid >> 6;
    const int lane = tid & 63;
    const int l5   = lane >> 5;
    const int lr32 = lane & 31;
    const int wm = (wave >> 1) * 64;   // m (P-col) half
    const int wn = (wave & 1) * 64;    // n (P-row) half

    const int m0 = blockIdx.y * 128;
    const int n0 = blockIdx.x * 128;
    const int bz = blockIdx.z;

    const unsigned char* Ap = A + (size_t)bz * ((size_t)AREA * 1024) +
                              (size_t)m0 * 1024;
    const unsigned char* Bp = B + (size_t)bz * ((size_t)AREA * 1024) +
                              (size_t)n0 * 1024;

    unsigned int aOff[4];
#pragma unroll
    for (int r = 0; r < 4; ++r) {
        int idx = r * 256 + tid;
        int row = idx >> 3;
        int scc = (idx & 7) ^ (row & 7);
        aOff[r] = (unsigned int)(row * 1024 + (scc << 4));
    }
    const int ra = wm + lr32;
    const int rb = wn + lr32;
    const int aB = ra * BKB + (((l5 << 1) ^ (ra & 7)) << 4);
    const int bB = rb * BKB + (((l5 << 1) ^ (rb & 7)) << 4);

    floatx16 acc[2][2];    // [ia = m frag][jb = n frag]
#pragma unroll
    for (int i = 0; i < 2; ++i)
#pragma unroll
        for (int j = 0; j < 2; ++j)
#pragma unroll
            for (int r = 0; r < 16; ++r) acc[i][j][r] = 0.f;

    for (int k0 = 0; k0 < 512; k0 += BKB) {
#pragma unroll
        for (int r = 0; r < 4; ++r)
            async_copy16(Ap + k0 + aOff[r], &As[(r * 256 + tid) * 16]);
#pragma unroll
        for (int r = 0; r < 4; ++r)
            async_copy16(Bp + k0 + aOff[r], &Bs[(r * 256 + tid) * 16]);
        __syncthreads();
#pragma unroll
        for (int kh = 0; kh < 2; ++kh) {             // K=64 per step
            intx8 af[2], bg[2];
#pragma unroll
            for (int i = 0; i < 2; ++i) {
                int o = (aB + i * 32 * BKB) ^ (kh << 6);
                intx4 lo = *(const intx4*)&As[o];
                intx4 hi = *(const intx4*)&As[o ^ 16];
                af[i] = __builtin_shufflevector(lo, hi, 0, 1, 2, 3, 4, 5, 6, 7);
            }
#pragma unroll
            for (int j = 0; j < 2; ++j) {
                int o = (bB + j * 32 * BKB) ^ (kh << 6);
                intx4 lo = *(const intx4*)&Bs[o];
                intx4 hi = *(const intx4*)&Bs[o ^ 16];
                bg[j] = __builtin_shufflevector(lo, hi, 0, 1, 2, 3, 4, 5, 6, 7);
            }
#pragma unroll
            for (int i = 0; i < 2; ++i)
#pragma unroll
                for (int j = 0; j < 2; ++j)
                    acc[i][j] = __builtin_amdgcn_mfma_scale_f32_32x32x64_f8f6f4(
                        af[i], bg[j], acc[i][j], 0, 0,
                        0, 0x7f7f7f7f, 0, 0x7f7f7f7f);
        }
        __syncthreads();
    }

    // ---- epilogue: exp2 + fp8 pack via Ct bounce (aliases As+Bs) ----
    unsigned char* Ct = smem;                   // 128*144 = 18432 <= 32768
    const float ec1  = 0.044194173824159216f * 1.44269504f;  // (1/sqrt c)*log2e
    const float mec2 = -5.77078016f;                          // -4*log2(e)
    float* ls = lsum + (size_t)bz * AREA;
#pragma unroll
    for (int jb = 0; jb < 2; ++jb) {
        const int nl = wn + jb * 32 + lr32;     // local P row
        float rs = 0.f;
#pragma unroll
        for (int ia = 0; ia < 2; ++ia) {
#pragma unroll
            for (int g = 0; g < 4; ++g) {
                float e0 = exp2f(fmaf(acc[ia][jb][g * 4 + 0], ec1, mec2));
                float e1 = exp2f(fmaf(acc[ia][jb][g * 4 + 1], ec1, mec2));
                float e2 = exp2f(fmaf(acc[ia][jb][g * 4 + 2], ec1, mec2));
                float e3 = exp2f(fmaf(acc[ia][jb][g * 4 + 3], ec1, mec2));
                rs += (e0 + e1) + (e2 + e3);
                int pk = __builtin_amdgcn_cvt_pk_fp8_f32(e0, e1, 0, false);
                pk = __builtin_amdgcn_cvt_pk_fp8_f32(e2, e3, pk, true);
                *(unsigned int*)&Ct[nl * 144 + wm + ia * 32 + g * 8 + l5 * 4] =
                    (unsigned int)pk;
            }
        }
        rs += __shfl_xor(rs, 32);
        if (l5 == 0) atomicAdd(&ls[n0 + nl], rs);
    }
    __syncthreads();
    const int row  = tid >> 1;
    const int half = (tid & 1) * 64;
    unsigned char* dstp = P + (size_t)bz * ((size_t)AREA * AREA) +
                          (size_t)(n0 + row) * AREA + m0 + half;
    const unsigned char* srcp = &Ct[row * 144 + half];
#pragma unroll
    for (int k = 0; k < 4; ++k)
        *(uint4*)(dstp + k * 16) = *(const uint4*)(srcp + k * 16);
}

// =====================================================================
// PV via MX-scaled fp8 MFMA (scales = 1.0), BKB=256 / 64 KB LDS,
// launch_bounds(256,2) + XCD-chunk swizzle [round-12 proven, +7us]:
// C[m][n] = (sum_k A[m][k]*B[n][k]) / lsum[m], bf16 out.
// =====================================================================
__global__ __launch_bounds__(256, 2) void pv_mx(
    const unsigned char* __restrict__ A, const unsigned char* __restrict__ B,
    unsigned short* __restrict__ C, const float* __restrict__ lsum,
    int M, int N, int K, int lda, int ldb, int ldc,
    long sA, long sB, long sC)
{
    constexpr int TBM = 128, TBN = 128, BKB = 256;
    __shared__ __align__(16) unsigned char As[TBM * BKB];   // 32 KB
    __shared__ __align__(16) unsigned char Bs[TBN * BKB];   // 32 KB

    const int tid  = threadIdx.x;
    const int wave = tid >> 6;
    const int lane = tid & 63;
    const int l5   = lane >> 5;
    const int lr32 = lane & 31;
    const int wm = (wave >> 1) * 64;
    const int wn = (wave & 1) * 64;

    // XCD-chunk swizzle: grid (4,32,4)=512 blocks; 64-block chunk/XCD.
    const int f   = blockIdx.x + 4 * (blockIdx.y + 32 * blockIdx.z);
    const int wid = ((f & 7) << 6) + (f >> 3);
    const int bx  = wid & 3;
    const int by  = (wid >> 2) & 31;
    const int bz  = wid >> 7;

    const int m0 = by * TBM;
    const int n0 = bx * TBN;
    A += (size_t)bz * sA + (size_t)m0 * lda;
    B += (size_t)bz * sB + (size_t)n0 * ldb;

    unsigned int aOff[8], bOff[8];
#pragma unroll
    for (int r = 0; r < 8; ++r) {
        int idx = r * 256 + tid;
        int row = idx >> 4;
        int scc = (idx & 15) ^ (row & 7);
        aOff[r] = (unsigned int)(row * lda + (scc << 4));
        bOff[r] = (unsigned int)(row * ldb + (scc << 4));
    }
    const int ra = wm + lr32;
    const int rb = wn + lr32;
    const int aB = ra * BKB + (((l5 << 1) ^ (ra & 7)) << 4);
    const int bB = rb * BKB + (((l5 << 1) ^ (rb & 7)) << 4);

    floatx16 acc[2][2];
#pragma unroll
    for (int i = 0; i < 2; ++i)
#pragma unroll
        for (int j = 0; j < 2; ++j)
#pragma unroll
            for (int r = 0; r < 16; ++r) acc[i][j][r] = 0.f;

    const char* Ab = (const char*)A;
    const char* Bb = (const char*)B;
    for (int k0 = 0; k0 < K; k0 += BKB) {
#pragma unroll
        for (int r = 0; r < 8; ++r)
            async_copy16(Ab + aOff[r], &As[(r * 256 + tid) * 16]);
#pragma unroll
        for (int r = 0; r < 8; ++r)
            async_copy16(Bb + bOff[r], &Bs[(r * 256 + tid) * 16]);
        Ab += BKB;
        Bb += BKB;
        __syncthreads();
#pragma unroll
        for (int kh = 0; kh < 4; ++kh) {             // K=64 per step
            intx8 af[2], bg[2];
#pragma unroll
            for (int i = 0; i < 2; ++i) {
                int o = (aB + i * 32 * BKB) ^ (kh << 6);
                intx4 lo = *(const intx4*)&As[o];
                intx4 hi = *(const intx4*)&As[o ^ 16];
                af[i] = __builtin_shufflevector(lo, hi, 0, 1, 2, 3, 4, 5, 6, 7);
            }
#pragma unroll
            for (int j = 0; j < 2; ++j) {
                int o = (bB + j * 32 * BKB) ^ (kh << 6);
                intx4 lo = *(const intx4*)&Bs[o];
                intx4 hi = *(const intx4*)&Bs[o ^ 16];
                bg[j] = __builtin_shufflevector(lo, hi, 0, 1, 2, 3, 4, 5, 6, 7);
            }
#pragma unroll
            for (int i = 0; i < 2; ++i)
#pragma unroll
                for (int j = 0; j < 2; ++j)
                    acc[i][j] = __builtin_amdgcn_mfma_scale_f32_32x32x64_f8f6f4(
                        af[i], bg[j], acc[i][j], 0, 0,
                        0, 0x7f7f7f7f, 0, 0x7f7f7f7f);
        }
        __syncthreads();
    }

    C += (size_t)bz * sC;
    const float* ls = lsum + (size_t)bz * M;
#pragma unroll
    for (int i = 0; i < 2; ++i) {
        const int mb = m0 + wm + i * 32 + 4 * l5;
        float inv16[16];
#pragma unroll
        for (int r = 0; r < 16; ++r)
            inv16[r] = 1.0f / ls[mb + (r & 3) + 8 * (r >> 2)];
#pragma unroll
        for (int j = 0; j < 2; ++j) {
            const int nn = n0 + wn + j * 32 + lr32;
#pragma unroll
            for (int r = 0; r < 16; ++r) {
                const int m = mb + (r & 3) + 8 * (r >> 2);
                C[(size_t)m * ldc + nn] = f2bf(acc[i][j][r] * inv16[r]);
            }
        }
    }
}

// =====================================================================
// Prep: blocks [0,1024): GN stats partials; blocks [1024,2048):
// weight cvt — wq/wk/wv now fp8 (feeds MX GEMMs), wo stays bf16.
// =====================================================================
__global__ __launch_bounds__(256) void prep(
    const float* __restrict__ net, float2* __restrict__ part,
    const float* __restrict__ wq, const float* __restrict__ wk,
    const float* __restrict__ wv, const float* __restrict__ wo,
    const float* __restrict__ bq, const float* __restrict__ bk,
    unsigned char* __restrict__ wqk8, unsigned char* __restrict__ wv8,
    unsigned short* __restrict__ wob, float* __restrict__ bqk)
{
    if (blockIdx.x < 1024) {
        const int bg = blockIdx.x >> 3, q = blockIdx.x & 7;
        const float4* p = (const float4*)(net + (size_t)bg * 65536 + q * 8192);
        float s = 0.f, ss = 0.f;
#pragma unroll
        for (int i = 0; i < 8; ++i) {
            float4 v = p[threadIdx.x + i * 256];
            s  += v.x + v.y + v.z + v.w;
            ss += v.x * v.x + v.y * v.y + v.z * v.z + v.w * v.w;
        }
#pragma unroll
        for (int o = 32; o; o >>= 1) { s += __shfl_xor(s, o); ss += __shfl_xor(ss, o); }
        __shared__ float rs[4], rss[4];
        const int wave = threadIdx.x >> 6, lane = threadIdx.x & 63;
        if (lane == 0) { rs[wave] = s; rss[wave] = ss; }
        __syncthreads();
        if (threadIdx.x == 0) {
            float2 o;
            o.x = rs[0] + rs[1] + rs[2] + rs[3];
            o.y = rss[0] + rss[1] + rss[2] + rss[3];
            part[bg * 8 + q] = o;
        }
    } else {
        const int blk = blockIdx.x - 1024;
        const int i = blk * 256 + threadIdx.x;
        wqk8[i]          = f2f8(wq[i]);
        wqk8[262144 + i] = f2f8(wk[i]);
        wv8[i] = f2f8(wv[i]);
        wob[i] = f2bf(wo[i]);
        if (i < 512) { bqk[i] = bq[i]; bqk[512 + i] = bk[i]; }
    }
}

// =====================================================================
// Normalize + transpose (+inline stats finalize):
// net[b][c][a] fp32 -> xn8[b][a][c] fp8 (feeds MX QK / V GEMMs)
// =====================================================================
__global__ __launch_bounds__(256) void gn_norm_t(
    const float* __restrict__ net, const float2* __restrict__ part,
    const float* __restrict__ gamma, const float* __restrict__ beta,
    unsigned char* __restrict__ xn8)
{
    __shared__ float tile[64][65];
    const int b = blockIdx.z, c0 = blockIdx.y * 64, a0 = blockIdx.x * 64;
    const int tq = threadIdx.x >> 6;
    const int tl = threadIdx.x & 63;
    float mu4[4], rs4[4];
#pragma unroll
    for (int gg = 0; gg < 4; ++gg) {
        int g = (c0 >> 4) + gg;
        float s = 0.f, ss = 0.f;
#pragma unroll
        for (int j = 0; j < 8; ++j) {
            float2 p = part[(b * NGRP + g) * 8 + j];
            s += p.x; ss += p.y;
        }
        float mu = s * (1.f / 65536.f);
        mu4[gg] = mu;
        rs4[gg] = rsqrtf(ss * (1.f / 65536.f) - mu * mu + 1e-6f);
    }
    const float* src = net + ((size_t)b * CCH + c0) * AREA + a0;
#pragma unroll
    for (int p = 0; p < 16; ++p) {
        int cr = p * 4 + tq;
        int c  = c0 + cr;
        int gg = cr >> 4;
        float x = src[(size_t)cr * AREA + tl];
        tile[cr][tl] = (x - mu4[gg]) * rs4[gg] * gamma[c] + beta[c];
    }
    __syncthreads();
    // write fp8, 4 channels/thread packed as uint (coalesced)
    unsigned char* dst = xn8 + ((size_t)b * AREA + a0) * CCH + c0;
    const int cb = (threadIdx.x & 15) * 4;
#pragma unroll
    for (int p = 0; p < 4; ++p) {
        int ar = p * 16 + (threadIdx.x >> 4);
        int pk = __builtin_amdgcn_cvt_pk_fp8_f32(tile[cb][ar], tile[cb + 1][ar],
                                                 0, false);
        pk = __builtin_amdgcn_cvt_pk_fp8_f32(tile[cb + 2][ar], tile[cb + 3][ar],
                                             pk, true);
        *(unsigned int*)&dst[(size_t)ar * CCH + cb] = (unsigned int)pk;
    }
}

// =====================================================================
// Host launch
// =====================================================================
extern "C" void kernel_launch(void* const* d_in, const int* in_sizes, int n_in,
                              void* d_out, int out_size, void* d_ws, size_t ws_size,
                              hipStream_t stream)
{
    (void)in_sizes; (void)n_in; (void)out_size; (void)ws_size;
    const float* net      = (const float*)d_in[0];
    const float* gn_scale = (const float*)d_in[1];
    const float* gn_bias  = (const float*)d_in[2];
    const float* wq = (const float*)d_in[3];
    const float* bq = (const float*)d_in[4];
    const float* wk = (const float*)d_in[5];
    const float* bk = (const float*)d_in[6];
    const float* wv = (const float*)d_in[7];
    const float* bv = (const float*)d_in[8];
    const float* wo = (const float*)d_in[9];
    const float* bo = (const float*)d_in[10];
    float* out = (float*)d_out;
    char* ws = (char*)d_ws;

    // workspace layout (bytes), high-water 140 MB:
    //   [       0,  1.5M) wqk8(512K fp8) wv8(256K fp8) wob(512K bf16)
    //   [    2.0M,  2.2M) bqk, part, lsum
    //   [    4.0M, 12.0M) xn8 [b][a][c] fp8
    //   [   20.0M, 36.0M) qkT [b][a][1024] fp8  (q | k per row)
    //   [   52.0M, 60.0M) vB  [b][c][a] fp8
    //   [   60.0M, 76.0M) hT  [b][a][c] bf16
    //   [   76.0M,140.0M) Pall fp8 e4m3
    unsigned char*  wqk8 = (unsigned char*)(ws + 0);
    unsigned char*  wv8  = (unsigned char*)(ws + 524288);
    unsigned short* wob  = (unsigned short*)(ws + 786432);
    float*          bqk  = (float*)(ws + 2097152);
    float2*         part = (float2*)(ws + 2105344);
    float*          lsum = (float*)(ws + 2121728);
    unsigned char*  xn8  = (unsigned char*)(ws + 4194304);
    unsigned char*  qkT  = (unsigned char*)(ws + 20971520);
    unsigned char*  vB   = (unsigned char*)(ws + 54525952);
    unsigned short* hT   = (unsigned short*)(ws + 62914560);
    unsigned char*  Pall = (unsigned char*)(ws + 79691776);

    const long PB  = (long)AREA * AREA;              // P bytes per batch
    const long tb  = (long)TB;                       // 2M (elems = bytes fp8)
    const long qks = (long)AREA * 1024;              // qkT batch stride (B)

    hipMemsetAsync(lsum, 0, 4 * AREA * sizeof(float), stream);
    prep<<<2048, 256, 0, stream>>>(net, part, wq, wk, wv, wo, bq, bk,
                                   wqk8, wv8, wob, bqk);
    gn_norm_t<<<dim3(64, 8, 4), 256, 0, stream>>>(net, part, gn_scale, gn_bias, xn8);

    // QK (MX fp8): qkT[b][a][n] = fp8(sum_c xn8[a][c]*wqk8[n][c] + bqk[n])
    gemm_mx<2><<<dim3(8, 32, 4), 256, 0, stream>>>(
        xn8, wqk8, qkT, bqk,
        AREA, 1024, CCH, CCH, CCH, 1024, tb, 0, qks);

    // S+exp MX fp8 (BKB=128): Pall[b][i][j] = fp8(exp(s/sqrt(c) - 4)); lsum rows.
    s_mx<<<dim3(32, 32, 4), 256, 0, stream>>>(qkT + 512, qkT, Pall, lsum);

    // V (MX fp8): vB[b][o][a] = fp8(sum_c wv8[o][c]*xn8[a][c] + bv[o])
    gemm_mx<1><<<dim3(32, 4, 4), 256, 0, stream>>>(
        wv8, xn8, vB, bv,
        CCH, AREA, CCH, CCH, CCH, AREA, 0, tb, tb);

    // PV (MX fp8, scales=1, BKB=256, XCD-swizzled): hT = (P @ V^T) / lsum
    pv_mx<<<dim3(4, 32, 4), 256, 0, stream>>>(Pall, vB, hT, lsum,
            AREA, CCH, AREA, AREA, AREA, CCH, PB, tb, tb);

    // out[b][o][a] = net + bo[o] + sum_c wo[o][c]*hT[a][c]
    gemm_tn<128, 128, float, 1, true>
        <<<dim3(32, 4, 4), 256, 0, stream>>>(wob, hT, out, bo, net,
            CCH, AREA, CCH, CCH, CCH, AREA, 0, tb, tb, tb, 1.0f);
}